// Round 7
// baseline (67.441 us; speedup 1.0000x reference)
//
#include <hip/hip_runtime.h>
#include <stdint.h>

#define B_ 4
#define C_ 512
#define N_ 4096
#define D_ 64
#define LOG2E 1.4426950408889634f

typedef __attribute__((ext_vector_type(8))) short short8;
typedef __attribute__((ext_vector_type(4))) float f32x4;
typedef __attribute__((ext_vector_type(16))) float f32x16;
typedef unsigned short ushort_t;

static __device__ __forceinline__ ushort_t f2bf(float f) {
    union { float f; uint32_t u; } v; v.f = f;
    uint32_t u = v.u;
    uint32_t r = u + 0x7FFFu + ((u >> 16) & 1u);
    return (ushort_t)(r >> 16);
}
static __device__ __forceinline__ float bf2f(uint32_t u) {
    union { uint32_t u; float f; } v; v.u = u << 16;
    return v.f;
}
static __device__ __forceinline__ uint32_t cvtpk_bf16(float lo, float hi) {
    uint32_t r;
    asm("v_cvt_pk_bf16_f32 %0, %1, %2" : "=v"(r) : "v"(lo), "v"(hi));
    return r;
}
// async global->LDS, 16B per lane. LDS dst must be wave-uniform base + lane*16.
static __device__ __forceinline__ void gl16(const ushort_t* g, ushort_t* l) {
    __builtin_amdgcn_global_load_lds(
        (const __attribute__((address_space(1))) void*)g,
        (__attribute__((address_space(3))) void*)l, 16, 0, 0);
}

// -------------------------------------------------------------------------
// Kernel 1: merged F/G/H projections, 512 threads, BK=64 (8 chunks, half the
// barriers of R5's BK=32). As stride 66: write-side conflicts 8-way -> 4-way.
// F gets LOG2E folded in; F -> Ftf, H -> Vtf in attn-fragment order
// (epilogue layouts verified R3-R6).
// -------------------------------------------------------------------------
__global__ __launch_bounds__(512) void proj_fgh(
    const float* __restrict__ x,
    const float* __restrict__ wf, const float* __restrict__ bf,
    const float* __restrict__ wg, const float* __restrict__ bg,
    const float* __restrict__ wh, const float* __restrict__ bh,
    ushort_t* __restrict__ Ftf, ushort_t* __restrict__ Gt,
    ushort_t* __restrict__ Vtf)
{
    const int b    = blockIdx.y;
    const int tile = blockIdx.x;
    const int n0   = tile * 64;
    const int tid  = threadIdx.x;          // 0..511
    const int wv   = tid >> 6;             // 0..7
    const int mw   = wv & 3;
    const int hi   = wv >> 2;
    const int lane = tid & 63;
    const int g    = lane >> 4;
    const int r    = lane & 15;

    __shared__ ushort_t As[64][66];        // [loc][k], BK=64
    __shared__ ushort_t Bs[192][66];       // [o][k]

    f32x4 acc[6];
    #pragma unroll
    for (int t = 0; t < 6; ++t) acc[t] = (f32x4){0.f, 0.f, 0.f, 0.f};

    const int ka  = tid >> 4;              // 0..31 (k row; +32 for 2nd half)
    const int mb  = (tid & 15) * 4;        // 0..60 (4 locs)
    const int ow2 = tid >> 4;              // 0..31 (o row within 32-group)
    const int kb2 = (tid & 15) * 4;        // 0..60 (k offset)

    const float* xp = x + ((size_t)b * C_ + ka) * N_ + n0 + mb;
    const float* wp[6];
    wp[0] = wf + (size_t)ow2 * C_ + kb2;
    wp[1] = wf + (size_t)(32 + ow2) * C_ + kb2;
    wp[2] = wg + (size_t)ow2 * C_ + kb2;
    wp[3] = wg + (size_t)(32 + ow2) * C_ + kb2;
    wp[4] = wh + (size_t)ow2 * C_ + kb2;
    wp[5] = wh + (size_t)(32 + ow2) * C_ + kb2;

    // prefetch chunk 0
    float4 xa0 = *(const float4*)xp;
    float4 xa1 = *(const float4*)(xp + (size_t)32 * N_);
    float4 wr[6];
    #pragma unroll
    for (int it = 0; it < 6; ++it) wr[it] = *(const float4*)wp[it];

    for (int k0 = 0; k0 < C_; k0 += 64) {
        // ---- stage A (transpose x into [loc][k])
        As[mb + 0][ka] = f2bf(xa0.x);
        As[mb + 1][ka] = f2bf(xa0.y);
        As[mb + 2][ka] = f2bf(xa0.z);
        As[mb + 3][ka] = f2bf(xa0.w);
        As[mb + 0][ka + 32] = f2bf(xa1.x);
        As[mb + 1][ka + 32] = f2bf(xa1.y);
        As[mb + 2][ka + 32] = f2bf(xa1.z);
        As[mb + 3][ka + 32] = f2bf(xa1.w);
        // ---- stage B (cvtpk-packed weight rows)
        #pragma unroll
        for (int it = 0; it < 6; ++it) {
            const int o = it * 32 + ow2;
            uint2 pk;
            pk.x = cvtpk_bf16(wr[it].x, wr[it].y);
            pk.y = cvtpk_bf16(wr[it].z, wr[it].w);
            *(uint2*)&Bs[o][kb2] = pk;
        }
        // ---- prefetch next chunk (register double-buffer, spans the barrier)
        if (k0 + 64 < C_) {
            xa0 = *(const float4*)(xp + (size_t)(k0 + 64) * N_);
            xa1 = *(const float4*)(xp + (size_t)(k0 + 96) * N_);
            #pragma unroll
            for (int it = 0; it < 6; ++it)
                wr[it] = *(const float4*)(wp[it] + k0 + 64);
        }
        __syncthreads();
        const short8 a0 = *(const short8*)&As[16 * mw + r][8 * g];
        const short8 a1 = *(const short8*)&As[16 * mw + r][32 + 8 * g];
        __builtin_amdgcn_s_setprio(1);
        #pragma unroll
        for (int tt = 0; tt < 6; ++tt) {
            const int T = hi * 6 + tt;
            const short8 b0 = *(const short8*)&Bs[T * 16 + r][8 * g];
            acc[tt] = __builtin_amdgcn_mfma_f32_16x16x32_bf16(a0, b0, acc[tt], 0, 0, 0);
            const short8 b1 = *(const short8*)&Bs[T * 16 + r][32 + 8 * g];
            acc[tt] = __builtin_amdgcn_mfma_f32_16x16x32_bf16(a1, b1, acc[tt], 0, 0, 0);
        }
        __builtin_amdgcn_s_setprio(0);
        __syncthreads();
    }

    // ---- G: direct store (rows of Gt)
    #pragma unroll
    for (int u = 0; u < 2; ++u) {
        const int tt = hi ? u : (4 + u);
        const int og = hi ? (32 + u * 16 + r) : (u * 16 + r);
        const float bvv = bg[og];
        #pragma unroll
        for (int j = 0; j < 4; ++j) {
            const int loc = n0 + 16 * mw + 4 * g + j;
            Gt[((size_t)b * N_ + loc) * D_ + og] = f2bf(acc[tt][j] + bvv);
        }
    }

    ushort_t (*bb)[72] = (ushort_t(*)[72])Bs;

    // ---- F -> bb -> Ftf (fragment order), LOG2E folded. Waves 0-3 own F.
    if (hi == 0) {
        #pragma unroll
        for (int tt = 0; tt < 4; ++tt) {
            const int o = tt * 16 + r;
            const float bvv = bf[o];
            #pragma unroll
            for (int j = 0; j < 4; ++j)
                bb[16 * mw + 4 * g + j][o] = f2bf((acc[tt][j] + bvv) * LOG2E);
        }
    }
    __syncthreads();
    {
        const int f  = wv;                 // 0..7 = cc*4 + s
        const int cc = f >> 2, s = f & 3;
        short8 v = *(const short8*)&bb[32 * cc + (lane & 31)][16 * s + 8 * (lane >> 5)];
        *(short8*)&Ftf[(((size_t)b * 64 + tile) * 8 + f) * 512 + lane * 8] = v;
    }
    __syncthreads();

    // ---- H -> bb -> Vtf (fragment order). Waves 4-7 own H.
    if (hi == 1) {
        #pragma unroll
        for (int tt = 2; tt < 6; ++tt) {
            const int o = (tt - 2) * 16 + r;
            const float bvv = bh[o];
            #pragma unroll
            for (int j = 0; j < 4; ++j)
                bb[16 * mw + 4 * g + j][o] = f2bf(acc[tt][j] + bvv);
        }
    }
    __syncthreads();
    {
        const int f   = wv;                // cc*4 + sub*2 + dt
        const int cc  = f >> 2, sub = (f >> 1) & 1, dt = f & 1;
        const int h2l = lane >> 5;
        short8 v;
        #pragma unroll
        for (int e = 0; e < 8; ++e) {
            const int i = 32 * cc + 16 * sub + (e & 3) + 8 * (e >> 2) + 4 * h2l;
            v[e] = (short)bb[i][32 * dt + (lane & 31)];
        }
        *(short8*)&Vtf[(((size_t)b * 64 + tile) * 8 + f) * 512 + lane * 8] = v;
    }
}

// -------------------------------------------------------------------------
// Kernel 2: flash attention (R5 structure — verified fastest config).
// 32x32x16 MFMA, split-K, Q=32/wave, 1024 blocks (4/CU, 4 waves/SIMD).
// Max-free exact softmax; sync -> prefetch-issue -> compute loop order.
// -------------------------------------------------------------------------
__global__ __launch_bounds__(256, 4) void attn(
    const ushort_t* __restrict__ Ftf, const ushort_t* __restrict__ Gt,
    const ushort_t* __restrict__ Vtf, ushort_t* __restrict__ Ot,
    ushort_t* __restrict__ Op, float* __restrict__ ml, int ksplit)
{
    const int b    = blockIdx.z;
    const int part = blockIdx.y;
    const int tid  = threadIdx.x;
    const int wave = tid >> 6;
    const int lane = tid & 63;
    const int l31  = lane & 31;
    const int h2   = lane >> 5;
    const int j0   = blockIdx.x * 128 + wave * 32;
    const int NT   = (N_ / ksplit) / 64;
    const int kt0  = part * NT;

    __shared__ __align__(16) ushort_t Ks[2][4096];
    __shared__ __align__(16) ushort_t Vs[2][4096];

    const ushort_t* qrow = Gt + ((size_t)b * N_ + j0 + l31) * D_ + 8 * h2;
    const short8 qf0 = *(const short8*)(qrow);
    const short8 qf1 = *(const short8*)(qrow + 16);
    const short8 qf2 = *(const short8*)(qrow + 32);
    const short8 qf3 = *(const short8*)(qrow + 48);

    const ushort_t* Kt = Ftf + ((size_t)b * 64 + kt0) * 4096;
    const ushort_t* Vt = Vtf + ((size_t)b * 64 + kt0) * 4096;

    f32x16 oA, oB;
    #pragma unroll
    for (int q = 0; q < 16; ++q) { oA[q] = 0.f; oB[q] = 0.f; }
    float l_run = 0.f;

    // prologue: issue tile 0 DMA -> buf 0
    gl16(Kt + tid * 8,         &Ks[0][tid * 8]);
    gl16(Kt + (tid + 256) * 8, &Ks[0][(tid + 256) * 8]);
    gl16(Vt + tid * 8,         &Vs[0][tid * 8]);
    gl16(Vt + (tid + 256) * 8, &Vs[0][(tid + 256) * 8]);

    int buf = 0;
    for (int t = 0; t < NT; ++t) {
        __syncthreads();   // drains tile-t DMA (issued a full iter ago)
        if (t + 1 < NT) {
            const ushort_t* kg = Kt + (size_t)(t + 1) * 4096;
            const ushort_t* vg = Vt + (size_t)(t + 1) * 4096;
            const int nb = buf ^ 1;
            gl16(kg + tid * 8,         &Ks[nb][tid * 8]);
            gl16(kg + (tid + 256) * 8, &Ks[nb][(tid + 256) * 8]);
            gl16(vg + tid * 8,         &Vs[nb][tid * 8]);
            gl16(vg + (tid + 256) * 8, &Vs[nb][(tid + 256) * 8]);
        }
        #pragma unroll
        for (int cc = 0; cc < 2; ++cc) {
            const ushort_t* kb0 = &Ks[buf][cc * 2048];
            f32x16 sx;
            #pragma unroll
            for (int q = 0; q < 16; ++q) sx[q] = 0.f;
            __builtin_amdgcn_s_setprio(1);
            {
                const short8 k0 = *(const short8*)(kb0 + 0 * 512 + lane * 8);
                sx = __builtin_amdgcn_mfma_f32_32x32x16_bf16(k0, qf0, sx, 0, 0, 0);
                const short8 k1 = *(const short8*)(kb0 + 1 * 512 + lane * 8);
                sx = __builtin_amdgcn_mfma_f32_32x32x16_bf16(k1, qf1, sx, 0, 0, 0);
                const short8 k2 = *(const short8*)(kb0 + 2 * 512 + lane * 8);
                sx = __builtin_amdgcn_mfma_f32_32x32x16_bf16(k2, qf2, sx, 0, 0, 0);
                const short8 k3 = *(const short8*)(kb0 + 3 * 512 + lane * 8);
                sx = __builtin_amdgcn_mfma_f32_32x32x16_bf16(k3, qf3, sx, 0, 0, 0);
            }
            __builtin_amdgcn_s_setprio(0);

            // unshifted softmax numerator: p = 2^s  (exact; no max tracking)
            uint32_t pw[8];
            float cs = 0.f;
            #pragma unroll
            for (int q = 0; q < 8; ++q) {
                const float pa = __builtin_amdgcn_exp2f(sx[2 * q]);
                const float pb = __builtin_amdgcn_exp2f(sx[2 * q + 1]);
                cs += pa + pb;
                pw[q] = cvtpk_bf16(pa, pb);
            }
            l_run += cs;

            union { uint32_t w[4]; short8 v; } p0u, p1u;
            p0u.w[0] = pw[0]; p0u.w[1] = pw[1]; p0u.w[2] = pw[2]; p0u.w[3] = pw[3];
            p1u.w[0] = pw[4]; p1u.w[1] = pw[5]; p1u.w[2] = pw[6]; p1u.w[3] = pw[7];

            const ushort_t* vb0 = &Vs[buf][cc * 2048];
            __builtin_amdgcn_s_setprio(1);
            {
                const short8 v00 = *(const short8*)(vb0 + 0 * 512 + lane * 8);
                oA = __builtin_amdgcn_mfma_f32_32x32x16_bf16(v00, p0u.v, oA, 0, 0, 0);
                const short8 v01 = *(const short8*)(vb0 + 1 * 512 + lane * 8);
                oB = __builtin_amdgcn_mfma_f32_32x32x16_bf16(v01, p0u.v, oB, 0, 0, 0);
                const short8 v10 = *(const short8*)(vb0 + 2 * 512 + lane * 8);
                oA = __builtin_amdgcn_mfma_f32_32x32x16_bf16(v10, p1u.v, oA, 0, 0, 0);
                const short8 v11 = *(const short8*)(vb0 + 3 * 512 + lane * 8);
                oB = __builtin_amdgcn_mfma_f32_32x32x16_bf16(v11, p1u.v, oB, 0, 0, 0);
            }
            __builtin_amdgcn_s_setprio(0);
        }
        buf ^= 1;
    }

    const float lt = l_run + __shfl_xor(l_run, 32);

    if (ksplit == 1) {
        const float inv = 1.0f / lt;
        ushort_t* orow = Ot + ((size_t)b * N_ + j0 + l31) * D_;
        #pragma unroll
        for (int q = 0; q < 4; ++q) {
            const int d0 = 8 * q + 4 * h2;
            uint2 ua, ub;
            ua.x = cvtpk_bf16(oA[4 * q] * inv,     oA[4 * q + 1] * inv);
            ua.y = cvtpk_bf16(oA[4 * q + 2] * inv, oA[4 * q + 3] * inv);
            *(uint2*)&orow[d0] = ua;
            ub.x = cvtpk_bf16(oB[4 * q] * inv,     oB[4 * q + 1] * inv);
            ub.y = cvtpk_bf16(oB[4 * q + 2] * inv, oB[4 * q + 3] * inv);
            *(uint2*)&orow[32 + d0] = ub;
        }
    } else {
        ushort_t* orow = Op + (((size_t)b * ksplit + part) * N_ + j0 + l31) * D_;
        #pragma unroll
        for (int q = 0; q < 4; ++q) {
            const int d0 = 8 * q + 4 * h2;
            uint2 ua, ub;
            ua.x = cvtpk_bf16(oA[4 * q],     oA[4 * q + 1]);
            ua.y = cvtpk_bf16(oA[4 * q + 2], oA[4 * q + 3]);
            *(uint2*)&orow[d0] = ua;
            ub.x = cvtpk_bf16(oB[4 * q],     oB[4 * q + 1]);
            ub.y = cvtpk_bf16(oB[4 * q + 2], oB[4 * q + 3]);
            *(uint2*)&orow[32 + d0] = ub;
        }
        if (h2 == 0)
            ml[((size_t)b * ksplit + part) * N_ + j0 + l31] = lt;
    }
}

// -------------------------------------------------------------------------
// Kernel 2b: split-K reduce — plain weighted sum; 8 d per thread.
// -------------------------------------------------------------------------
__global__ __launch_bounds__(256) void reduce_attn(
    const ushort_t* __restrict__ Op, const float* __restrict__ ml,
    ushort_t* __restrict__ Ot, int ksplit)
{
    const int tid = blockIdx.x * 256 + threadIdx.x;   // over B*N*8
    const int d8 = (tid & 7) * 8;
    const int j  = (tid >> 3) & (N_ - 1);
    const int b  = tid >> 15;

    float L = 0.f;
    float v[8] = {0.f, 0.f, 0.f, 0.f, 0.f, 0.f, 0.f, 0.f};
    for (int p = 0; p < ksplit; ++p) {
        const size_t base = ((size_t)b * ksplit + p) * N_ + j;
        L += ml[base];
        uint4 u = *(const uint4*)&Op[base * D_ + d8];
        v[0] += bf2f(u.x & 0xffffu); v[1] += bf2f(u.x >> 16);
        v[2] += bf2f(u.y & 0xffffu); v[3] += bf2f(u.y >> 16);
        v[4] += bf2f(u.z & 0xffffu); v[5] += bf2f(u.z >> 16);
        v[6] += bf2f(u.w & 0xffffu); v[7] += bf2f(u.w >> 16);
    }
    const float inv = 1.0f / L;
    uint4 o;
    o.x = cvtpk_bf16(v[0] * inv, v[1] * inv);
    o.y = cvtpk_bf16(v[2] * inv, v[3] * inv);
    o.z = cvtpk_bf16(v[4] * inv, v[5] * inv);
    o.w = cvtpk_bf16(v[6] * inv, v[7] * inv);
    *(uint4*)&Ot[((size_t)b * N_ + j) * D_ + d8] = o;
}

// -------------------------------------------------------------------------
// Kernel 3: output projection + residual (verified since round 0).
// -------------------------------------------------------------------------
__global__ __launch_bounds__(256) void outproj(
    const ushort_t* __restrict__ Ot, const float* __restrict__ wv,
    const float* __restrict__ bv, const float* __restrict__ gamma,
    const float* __restrict__ x, float* __restrict__ y)
{
    const int b    = blockIdx.z;
    const int wave = threadIdx.x >> 6;
    const int lane = threadIdx.x & 63;
    const int g    = lane >> 4;
    const int r    = lane & 15;
    const int co0  = blockIdx.y * 64 + wave * 16;
    const int n0   = blockIdx.x * 64;

    const float* wrow = wv + (size_t)(co0 + r) * D_ + 8 * g;
    short8 a0, a1;
    #pragma unroll
    for (int j = 0; j < 8; ++j) {
        a0[j] = (short)f2bf(wrow[j]);
        a1[j] = (short)f2bf(wrow[32 + j]);
    }

    f32x4 acc[4];
    #pragma unroll
    for (int t = 0; t < 4; ++t) acc[t] = (f32x4){0.f, 0.f, 0.f, 0.f};

    #pragma unroll
    for (int t = 0; t < 4; ++t) {
        const ushort_t* op = Ot + ((size_t)b * N_ + n0 + 16 * t + r) * D_ + 8 * g;
        short8 b0 = *(const short8*)op;
        short8 b1 = *(const short8*)(op + 32);
        acc[t] = __builtin_amdgcn_mfma_f32_16x16x32_bf16(a0, b0, acc[t], 0, 0, 0);
        acc[t] = __builtin_amdgcn_mfma_f32_16x16x32_bf16(a1, b1, acc[t], 0, 0, 0);
    }

    const float gm = *gamma;
    #pragma unroll
    for (int t = 0; t < 4; ++t) {
        #pragma unroll
        for (int j = 0; j < 4; ++j) {
            const int co = co0 + 4 * g + j;
            const int n  = n0 + 16 * t + r;
            const size_t idx = ((size_t)b * C_ + co) * N_ + n;
            y[idx] = gm * (acc[t][j] + bv[co]) + x[idx];
        }
    }
}

// -------------------------------------------------------------------------
extern "C" void kernel_launch(void* const* d_in, const int* in_sizes, int n_in,
                              void* d_out, int out_size, void* d_ws, size_t ws_size,
                              hipStream_t stream) {
    const float* x     = (const float*)d_in[0];
    const float* wf    = (const float*)d_in[1];
    const float* bf    = (const float*)d_in[2];
    const float* wg    = (const float*)d_in[3];
    const float* bg    = (const float*)d_in[4];
    const float* wh    = (const float*)d_in[5];
    const float* bh    = (const float*)d_in[6];
    const float* wv    = (const float*)d_in[7];
    const float* bv    = (const float*)d_in[8];
    const float* gamma = (const float*)d_in[9];
    float* y = (float*)d_out;

    const size_t plane = (size_t)B_ * N_ * D_;   // 1M elements
    ushort_t* Ftf = (ushort_t*)d_ws;             // pre-swizzled K fragments
    ushort_t* Gt  = Ftf + plane;                 // Q rows
    ushort_t* Vtf = Gt + plane;                  // pre-swizzled V fragments
    ushort_t* Ot  = Vtf + plane;                 // attention output rows
    ushort_t* Op  = Ot + plane;                  // split-K partials (bf16)

    int KS = 8;
    while (KS > 1) {
        const size_t need = 4 * plane * 2 + (size_t)KS * plane * 2
                          + (size_t)B_ * KS * N_ * sizeof(float);
        if (need <= ws_size) break;
        KS >>= 1;
    }
    float* ml = (float*)(Op + (size_t)KS * plane);

    proj_fgh<<<dim3(N_ / 64, B_), 512, 0, stream>>>(
        x, wf, bf, wg, bg, wh, bh, Ftf, Gt, Vtf);
    attn<<<dim3(N_ / 128, KS, B_), 256, 0, stream>>>(
        Ftf, Gt, Vtf, Ot, Op, ml, KS);
    if (KS > 1)
        reduce_attn<<<(B_ * N_ * 8) / 256, 256, 0, stream>>>(Op, ml, Ot, KS);
    outproj<<<dim3(N_ / 64, C_ / 64, B_), 256, 0, stream>>>(Ot, wv, bv, gamma, x, y);
}

// Round 8
// 66.494 us; speedup vs baseline: 1.0142x; 1.0142x over previous
//
#include <hip/hip_runtime.h>
#include <stdint.h>

#define B_ 4
#define C_ 512
#define N_ 4096
#define D_ 64
#define LOG2E 1.4426950408889634f

typedef __attribute__((ext_vector_type(8))) short short8;
typedef __attribute__((ext_vector_type(4))) float f32x4;
typedef __attribute__((ext_vector_type(16))) float f32x16;
typedef unsigned short ushort_t;

static __device__ __forceinline__ ushort_t f2bf(float f) {
    union { float f; uint32_t u; } v; v.f = f;
    uint32_t u = v.u;
    uint32_t r = u + 0x7FFFu + ((u >> 16) & 1u);
    return (ushort_t)(r >> 16);
}
static __device__ __forceinline__ float bf2f(uint32_t u) {
    union { uint32_t u; float f; } v; v.u = u << 16;
    return v.f;
}
static __device__ __forceinline__ uint32_t cvtpk_bf16(float lo, float hi) {
    uint32_t r;
    asm("v_cvt_pk_bf16_f32 %0, %1, %2" : "=v"(r) : "v"(lo), "v"(hi));
    return r;
}

// -------------------------------------------------------------------------
// Kernel 1: merged F/G/H projections, 512 threads (R5 config — best measured).
// F gets LOG2E folded in; F -> Ftf, H -> Vtf in attn-fragment order.
// -------------------------------------------------------------------------
__global__ __launch_bounds__(512) void proj_fgh(
    const float* __restrict__ x,
    const float* __restrict__ wf, const float* __restrict__ bf,
    const float* __restrict__ wg, const float* __restrict__ bg,
    const float* __restrict__ wh, const float* __restrict__ bh,
    ushort_t* __restrict__ Ftf, ushort_t* __restrict__ Gt,
    ushort_t* __restrict__ Vtf)
{
    const int b    = blockIdx.y;
    const int tile = blockIdx.x;
    const int n0   = tile * 64;
    const int tid  = threadIdx.x;          // 0..511
    const int wv   = tid >> 6;             // 0..7
    const int mw   = wv & 3;
    const int hi   = wv >> 2;
    const int lane = tid & 63;
    const int g    = lane >> 4;
    const int r    = lane & 15;

    __shared__ ushort_t As[64][40];        // [loc][k]
    __shared__ ushort_t Bs[192][40];       // [o][k]

    f32x4 acc[6];
    #pragma unroll
    for (int t = 0; t < 6; ++t) acc[t] = (f32x4){0.f, 0.f, 0.f, 0.f};

    const int ka = tid >> 4;               // 0..31
    const int mb = (tid & 15) * 4;         // 0..60
    const int kb = (tid & 7) * 4;          // 0..28
    const int ow = tid >> 3;               // 0..63

    const float* xp  = x  + ((size_t)b * C_ + ka) * N_ + n0 + mb;
    const float* wp0 = wf + (size_t)ow * C_ + kb;
    const float* wp1 = wg + (size_t)ow * C_ + kb;
    const float* wp2 = wh + (size_t)ow * C_ + kb;

    float4 xa = *(const float4*)xp;
    float4 w0 = *(const float4*)wp0;
    float4 w1 = *(const float4*)wp1;
    float4 w2 = *(const float4*)wp2;

    for (int k0 = 0; k0 < C_; k0 += 32) {
        As[mb + 0][ka] = f2bf(xa.x);
        As[mb + 1][ka] = f2bf(xa.y);
        As[mb + 2][ka] = f2bf(xa.z);
        As[mb + 3][ka] = f2bf(xa.w);
        {
            uint2 p0, p1, p2;
            p0.x = cvtpk_bf16(w0.x, w0.y); p0.y = cvtpk_bf16(w0.z, w0.w);
            p1.x = cvtpk_bf16(w1.x, w1.y); p1.y = cvtpk_bf16(w1.z, w1.w);
            p2.x = cvtpk_bf16(w2.x, w2.y); p2.y = cvtpk_bf16(w2.z, w2.w);
            *(uint2*)&Bs[ow][kb]       = p0;
            *(uint2*)&Bs[64 + ow][kb]  = p1;
            *(uint2*)&Bs[128 + ow][kb] = p2;
        }
        if (k0 + 32 < C_) {
            xa = *(const float4*)(xp + (size_t)(k0 + 32) * N_);
            w0 = *(const float4*)(wp0 + k0 + 32);
            w1 = *(const float4*)(wp1 + k0 + 32);
            w2 = *(const float4*)(wp2 + k0 + 32);
        }
        __syncthreads();
        short8 a = *(const short8*)&As[16 * mw + r][8 * g];
        __builtin_amdgcn_s_setprio(1);
        #pragma unroll
        for (int tt = 0; tt < 6; ++tt) {
            const int T = hi * 6 + tt;
            short8 bbv = *(const short8*)&Bs[T * 16 + r][8 * g];
            acc[tt] = __builtin_amdgcn_mfma_f32_16x16x32_bf16(a, bbv, acc[tt], 0, 0, 0);
        }
        __builtin_amdgcn_s_setprio(0);
        __syncthreads();
    }

    // ---- G: direct store (rows of Gt)
    #pragma unroll
    for (int u = 0; u < 2; ++u) {
        const int tt = hi ? u : (4 + u);
        const int og = hi ? (32 + u * 16 + r) : (u * 16 + r);
        const float bvv = bg[og];
        #pragma unroll
        for (int j = 0; j < 4; ++j) {
            const int loc = n0 + 16 * mw + 4 * g + j;
            Gt[((size_t)b * N_ + loc) * D_ + og] = f2bf(acc[tt][j] + bvv);
        }
    }

    ushort_t (*bb)[72] = (ushort_t(*)[72])Bs;

    // ---- F -> bb -> Ftf (fragment order), LOG2E folded. Waves 0-3 own F.
    if (hi == 0) {
        #pragma unroll
        for (int tt = 0; tt < 4; ++tt) {
            const int o = tt * 16 + r;
            const float bvv = bf[o];
            #pragma unroll
            for (int j = 0; j < 4; ++j)
                bb[16 * mw + 4 * g + j][o] = f2bf((acc[tt][j] + bvv) * LOG2E);
        }
    }
    __syncthreads();
    {
        const int f  = wv;                 // 0..7 = cc*4 + s
        const int cc = f >> 2, s = f & 3;
        short8 v = *(const short8*)&bb[32 * cc + (lane & 31)][16 * s + 8 * (lane >> 5)];
        *(short8*)&Ftf[(((size_t)b * 64 + tile) * 8 + f) * 512 + lane * 8] = v;
    }
    __syncthreads();

    // ---- H -> bb -> Vtf (fragment order). Waves 4-7 own H.
    if (hi == 1) {
        #pragma unroll
        for (int tt = 2; tt < 6; ++tt) {
            const int o = (tt - 2) * 16 + r;
            const float bvv = bh[o];
            #pragma unroll
            for (int j = 0; j < 4; ++j)
                bb[16 * mw + 4 * g + j][o] = f2bf(acc[tt][j] + bvv);
        }
    }
    __syncthreads();
    {
        const int f   = wv;                // cc*4 + sub*2 + dt
        const int cc  = f >> 2, sub = (f >> 1) & 1, dt = f & 1;
        const int h2l = lane >> 5;
        short8 v;
        #pragma unroll
        for (int e = 0; e < 8; ++e) {
            const int i = 32 * cc + 16 * sub + (e & 3) + 8 * (e >> 2) + 4 * h2l;
            v[e] = (short)bb[i][32 * dt + (lane & 31)];
        }
        *(short8*)&Vtf[(((size_t)b * 64 + tile) * 8 + f) * 512 + lane * 8] = v;
    }
}

// -------------------------------------------------------------------------
// Kernel 2: flash attention — NO LDS, NO barriers. K/V fragments read
// directly from L2 (per-part slab = 128 KB, L2-resident; fragment-order
// layout makes every load a contiguous coalesced 1KB wave read; the 4
// waves of a block walk the same chunks ~in lockstep -> L1 reuse).
// Register prefetch of next chunk's K hides L2 latency under softmax+PV.
// 32x32x16 MFMA, Q=32/wave, split-K, max-free exact softmax (verified R5).
// -------------------------------------------------------------------------
__global__ __launch_bounds__(256, 3) void attn(
    const ushort_t* __restrict__ Ftf, const ushort_t* __restrict__ Gt,
    const ushort_t* __restrict__ Vtf, ushort_t* __restrict__ Ot,
    ushort_t* __restrict__ Op, float* __restrict__ ml, int ksplit)
{
    const int b    = blockIdx.z;
    const int part = blockIdx.y;
    const int tid  = threadIdx.x;
    const int wave = tid >> 6;
    const int lane = tid & 63;
    const int l31  = lane & 31;
    const int h2   = lane >> 5;
    const int j0   = blockIdx.x * 128 + wave * 32;
    const int NC   = (N_ / ksplit) / 32;    // 32-key chunks per part
    const int c0   = part * NC;

    const ushort_t* qrow = Gt + ((size_t)b * N_ + j0 + l31) * D_ + 8 * h2;
    const short8 qf0 = *(const short8*)(qrow);
    const short8 qf1 = *(const short8*)(qrow + 16);
    const short8 qf2 = *(const short8*)(qrow + 32);
    const short8 qf3 = *(const short8*)(qrow + 48);

    // per-chunk fragment base: chunk cg occupies elements [cg*2048, cg*2048+2048)
    const ushort_t* Kc = Ftf + (size_t)b * (N_ * D_) + (size_t)c0 * 2048 + lane * 8;
    const ushort_t* Vc = Vtf + (size_t)b * (N_ * D_) + (size_t)c0 * 2048 + lane * 8;

    f32x16 oA, oB;
    #pragma unroll
    for (int q = 0; q < 16; ++q) { oA[q] = 0.f; oB[q] = 0.f; }
    float l_run = 0.f;

    // prefetch chunk 0's K fragments
    short8 k0 = *(const short8*)(Kc);
    short8 k1 = *(const short8*)(Kc + 512);
    short8 k2 = *(const short8*)(Kc + 1024);
    short8 k3 = *(const short8*)(Kc + 1536);

    for (int c = 0; c < NC; ++c) {
        // V loads issue now, consumed after softmax (latency hidden)
        const ushort_t* vp = Vc + (size_t)c * 2048;
        const short8 v00 = *(const short8*)(vp);
        const short8 v01 = *(const short8*)(vp + 512);
        const short8 v10 = *(const short8*)(vp + 1024);
        const short8 v11 = *(const short8*)(vp + 1536);

        f32x16 sx;
        #pragma unroll
        for (int q = 0; q < 16; ++q) sx[q] = 0.f;
        __builtin_amdgcn_s_setprio(1);
        sx = __builtin_amdgcn_mfma_f32_32x32x16_bf16(k0, qf0, sx, 0, 0, 0);
        sx = __builtin_amdgcn_mfma_f32_32x32x16_bf16(k1, qf1, sx, 0, 0, 0);
        sx = __builtin_amdgcn_mfma_f32_32x32x16_bf16(k2, qf2, sx, 0, 0, 0);
        sx = __builtin_amdgcn_mfma_f32_32x32x16_bf16(k3, qf3, sx, 0, 0, 0);
        __builtin_amdgcn_s_setprio(0);

        // prefetch next chunk's K while softmax runs
        if (c + 1 < NC) {
            const ushort_t* kp = Kc + (size_t)(c + 1) * 2048;
            k0 = *(const short8*)(kp);
            k1 = *(const short8*)(kp + 512);
            k2 = *(const short8*)(kp + 1024);
            k3 = *(const short8*)(kp + 1536);
        }

        // unshifted softmax numerator: p = 2^s (exact; no max tracking)
        uint32_t pw[8];
        float cs = 0.f;
        #pragma unroll
        for (int q = 0; q < 8; ++q) {
            const float pa = __builtin_amdgcn_exp2f(sx[2 * q]);
            const float pb = __builtin_amdgcn_exp2f(sx[2 * q + 1]);
            cs += pa + pb;
            pw[q] = cvtpk_bf16(pa, pb);
        }
        l_run += cs;

        union { uint32_t w[4]; short8 v; } p0u, p1u;
        p0u.w[0] = pw[0]; p0u.w[1] = pw[1]; p0u.w[2] = pw[2]; p0u.w[3] = pw[3];
        p1u.w[0] = pw[4]; p1u.w[1] = pw[5]; p1u.w[2] = pw[6]; p1u.w[3] = pw[7];

        __builtin_amdgcn_s_setprio(1);
        oA = __builtin_amdgcn_mfma_f32_32x32x16_bf16(v00, p0u.v, oA, 0, 0, 0);
        oB = __builtin_amdgcn_mfma_f32_32x32x16_bf16(v01, p0u.v, oB, 0, 0, 0);
        oA = __builtin_amdgcn_mfma_f32_32x32x16_bf16(v10, p1u.v, oA, 0, 0, 0);
        oB = __builtin_amdgcn_mfma_f32_32x32x16_bf16(v11, p1u.v, oB, 0, 0, 0);
        __builtin_amdgcn_s_setprio(0);
    }

    const float lt = l_run + __shfl_xor(l_run, 32);

    if (ksplit == 1) {
        const float inv = 1.0f / lt;
        ushort_t* orow = Ot + ((size_t)b * N_ + j0 + l31) * D_;
        #pragma unroll
        for (int q = 0; q < 4; ++q) {
            const int d0 = 8 * q + 4 * h2;
            uint2 ua, ub;
            ua.x = cvtpk_bf16(oA[4 * q] * inv,     oA[4 * q + 1] * inv);
            ua.y = cvtpk_bf16(oA[4 * q + 2] * inv, oA[4 * q + 3] * inv);
            *(uint2*)&orow[d0] = ua;
            ub.x = cvtpk_bf16(oB[4 * q] * inv,     oB[4 * q + 1] * inv);
            ub.y = cvtpk_bf16(oB[4 * q + 2] * inv, oB[4 * q + 3] * inv);
            *(uint2*)&orow[32 + d0] = ub;
        }
    } else {
        ushort_t* orow = Op + (((size_t)b * ksplit + part) * N_ + j0 + l31) * D_;
        #pragma unroll
        for (int q = 0; q < 4; ++q) {
            const int d0 = 8 * q + 4 * h2;
            uint2 ua, ub;
            ua.x = cvtpk_bf16(oA[4 * q],     oA[4 * q + 1]);
            ua.y = cvtpk_bf16(oA[4 * q + 2], oA[4 * q + 3]);
            *(uint2*)&orow[d0] = ua;
            ub.x = cvtpk_bf16(oB[4 * q],     oB[4 * q + 1]);
            ub.y = cvtpk_bf16(oB[4 * q + 2], oB[4 * q + 3]);
            *(uint2*)&orow[32 + d0] = ub;
        }
        if (h2 == 0)
            ml[((size_t)b * ksplit + part) * N_ + j0 + l31] = lt;
    }
}

// -------------------------------------------------------------------------
// Kernel 2b: split-K reduce — plain weighted sum; 8 d per thread.
// -------------------------------------------------------------------------
__global__ __launch_bounds__(256) void reduce_attn(
    const ushort_t* __restrict__ Op, const float* __restrict__ ml,
    ushort_t* __restrict__ Ot, int ksplit)
{
    const int tid = blockIdx.x * 256 + threadIdx.x;   // over B*N*8
    const int d8 = (tid & 7) * 8;
    const int j  = (tid >> 3) & (N_ - 1);
    const int b  = tid >> 15;

    float L = 0.f;
    float v[8] = {0.f, 0.f, 0.f, 0.f, 0.f, 0.f, 0.f, 0.f};
    for (int p = 0; p < ksplit; ++p) {
        const size_t base = ((size_t)b * ksplit + p) * N_ + j;
        L += ml[base];
        uint4 u = *(const uint4*)&Op[base * D_ + d8];
        v[0] += bf2f(u.x & 0xffffu); v[1] += bf2f(u.x >> 16);
        v[2] += bf2f(u.y & 0xffffu); v[3] += bf2f(u.y >> 16);
        v[4] += bf2f(u.z & 0xffffu); v[5] += bf2f(u.z >> 16);
        v[6] += bf2f(u.w & 0xffffu); v[7] += bf2f(u.w >> 16);
    }
    const float inv = 1.0f / L;
    uint4 o;
    o.x = cvtpk_bf16(v[0] * inv, v[1] * inv);
    o.y = cvtpk_bf16(v[2] * inv, v[3] * inv);
    o.z = cvtpk_bf16(v[4] * inv, v[5] * inv);
    o.w = cvtpk_bf16(v[6] * inv, v[7] * inv);
    *(uint4*)&Ot[((size_t)b * N_ + j) * D_ + d8] = o;
}

// -------------------------------------------------------------------------
// Kernel 3: output projection + residual (verified since round 0).
// -------------------------------------------------------------------------
__global__ __launch_bounds__(256) void outproj(
    const ushort_t* __restrict__ Ot, const float* __restrict__ wv,
    const float* __restrict__ bv, const float* __restrict__ gamma,
    const float* __restrict__ x, float* __restrict__ y)
{
    const int b    = blockIdx.z;
    const int wave = threadIdx.x >> 6;
    const int lane = threadIdx.x & 63;
    const int g    = lane >> 4;
    const int r    = lane & 15;
    const int co0  = blockIdx.y * 64 + wave * 16;
    const int n0   = blockIdx.x * 64;

    const float* wrow = wv + (size_t)(co0 + r) * D_ + 8 * g;
    short8 a0, a1;
    #pragma unroll
    for (int j = 0; j < 8; ++j) {
        a0[j] = (short)f2bf(wrow[j]);
        a1[j] = (short)f2bf(wrow[32 + j]);
    }

    f32x4 acc[4];
    #pragma unroll
    for (int t = 0; t < 4; ++t) acc[t] = (f32x4){0.f, 0.f, 0.f, 0.f};

    #pragma unroll
    for (int t = 0; t < 4; ++t) {
        const ushort_t* op = Ot + ((size_t)b * N_ + n0 + 16 * t + r) * D_ + 8 * g;
        short8 b0 = *(const short8*)op;
        short8 b1 = *(const short8*)(op + 32);
        acc[t] = __builtin_amdgcn_mfma_f32_16x16x32_bf16(a0, b0, acc[t], 0, 0, 0);
        acc[t] = __builtin_amdgcn_mfma_f32_16x16x32_bf16(a1, b1, acc[t], 0, 0, 0);
    }

    const float gm = *gamma;
    #pragma unroll
    for (int t = 0; t < 4; ++t) {
        #pragma unroll
        for (int j = 0; j < 4; ++j) {
            const int co = co0 + 4 * g + j;
            const int n  = n0 + 16 * t + r;
            const size_t idx = ((size_t)b * C_ + co) * N_ + n;
            y[idx] = gm * (acc[t][j] + bv[co]) + x[idx];
        }
    }
}

// -------------------------------------------------------------------------
extern "C" void kernel_launch(void* const* d_in, const int* in_sizes, int n_in,
                              void* d_out, int out_size, void* d_ws, size_t ws_size,
                              hipStream_t stream) {
    const float* x     = (const float*)d_in[0];
    const float* wf    = (const float*)d_in[1];
    const float* bf    = (const float*)d_in[2];
    const float* wg    = (const float*)d_in[3];
    const float* bg    = (const float*)d_in[4];
    const float* wh    = (const float*)d_in[5];
    const float* bh    = (const float*)d_in[6];
    const float* wv    = (const float*)d_in[7];
    const float* bv    = (const float*)d_in[8];
    const float* gamma = (const float*)d_in[9];
    float* y = (float*)d_out;

    const size_t plane = (size_t)B_ * N_ * D_;   // 1M elements
    ushort_t* Ftf = (ushort_t*)d_ws;             // pre-swizzled K fragments
    ushort_t* Gt  = Ftf + plane;                 // Q rows
    ushort_t* Vtf = Gt + plane;                  // pre-swizzled V fragments
    ushort_t* Ot  = Vtf + plane;                 // attention output rows
    ushort_t* Op  = Ot + plane;                  // split-K partials (bf16)

    int KS = 8;
    while (KS > 1) {
        const size_t need = 4 * plane * 2 + (size_t)KS * plane * 2
                          + (size_t)B_ * KS * N_ * sizeof(float);
        if (need <= ws_size) break;
        KS >>= 1;
    }
    float* ml = (float*)(Op + (size_t)KS * plane);

    proj_fgh<<<dim3(N_ / 64, B_), 512, 0, stream>>>(
        x, wf, bf, wg, bg, wh, bh, Ftf, Gt, Vtf);
    attn<<<dim3(N_ / 128, KS, B_), 256, 0, stream>>>(
        Ftf, Gt, Vtf, Ot, Op, ml, KS);
    if (KS > 1)
        reduce_attn<<<(B_ * N_ * 8) / 256, 256, 0, stream>>>(Op, ml, Ot, KS);
    outproj<<<dim3(N_ / 64, C_ / 64, B_), 256, 0, stream>>>(Ot, wv, bv, gamma, x, y);
}

// Round 9
// 60.112 us; speedup vs baseline: 1.1219x; 1.1062x over previous
//
#include <hip/hip_runtime.h>
#include <stdint.h>

#define B_ 4
#define C_ 512
#define N_ 4096
#define D_ 64
#define LOG2E 1.4426950408889634f

typedef __attribute__((ext_vector_type(8))) short short8;
typedef __attribute__((ext_vector_type(4))) float f32x4;
typedef __attribute__((ext_vector_type(16))) float f32x16;
typedef unsigned short ushort_t;

static __device__ __forceinline__ ushort_t f2bf(float f) {
    union { float f; uint32_t u; } v; v.f = f;
    uint32_t u = v.u;
    uint32_t r = u + 0x7FFFu + ((u >> 16) & 1u);
    return (ushort_t)(r >> 16);
}
static __device__ __forceinline__ float bf2f(uint32_t u) {
    union { uint32_t u; float f; } v; v.u = u << 16;
    return v.f;
}
static __device__ __forceinline__ uint32_t cvtpk_bf16(float lo, float hi) {
    uint32_t r;
    asm("v_cvt_pk_bf16_f32 %0, %1, %2" : "=v"(r) : "v"(lo), "v"(hi));
    return r;
}
// async global->LDS, 16B per lane. LDS dst must be wave-uniform base + lane*16.
static __device__ __forceinline__ void gl16(const ushort_t* g, ushort_t* l) {
    __builtin_amdgcn_global_load_lds(
        (const __attribute__((address_space(1))) void*)g,
        (__attribute__((address_space(3))) void*)l, 16, 0, 0);
}

// -------------------------------------------------------------------------
// Kernel 1: merged F/G/H projections, 512 threads (R5 config — best measured).
// F gets LOG2E folded in; F -> Ftf, H -> Vtf in attn-fragment order.
// -------------------------------------------------------------------------
__global__ __launch_bounds__(512) void proj_fgh(
    const float* __restrict__ x,
    const float* __restrict__ wf, const float* __restrict__ bf,
    const float* __restrict__ wg, const float* __restrict__ bg,
    const float* __restrict__ wh, const float* __restrict__ bh,
    ushort_t* __restrict__ Ftf, ushort_t* __restrict__ Gt,
    ushort_t* __restrict__ Vtf)
{
    const int b    = blockIdx.y;
    const int tile = blockIdx.x;
    const int n0   = tile * 64;
    const int tid  = threadIdx.x;          // 0..511
    const int wv   = tid >> 6;             // 0..7
    const int mw   = wv & 3;
    const int hi   = wv >> 2;
    const int lane = tid & 63;
    const int g    = lane >> 4;
    const int r    = lane & 15;

    __shared__ ushort_t As[64][40];        // [loc][k]
    __shared__ ushort_t Bs[192][40];       // [o][k]

    f32x4 acc[6];
    #pragma unroll
    for (int t = 0; t < 6; ++t) acc[t] = (f32x4){0.f, 0.f, 0.f, 0.f};

    const int ka = tid >> 4;               // 0..31
    const int mb = (tid & 15) * 4;         // 0..60
    const int kb = (tid & 7) * 4;          // 0..28
    const int ow = tid >> 3;               // 0..63

    const float* xp  = x  + ((size_t)b * C_ + ka) * N_ + n0 + mb;
    const float* wp0 = wf + (size_t)ow * C_ + kb;
    const float* wp1 = wg + (size_t)ow * C_ + kb;
    const float* wp2 = wh + (size_t)ow * C_ + kb;

    float4 xa = *(const float4*)xp;
    float4 w0 = *(const float4*)wp0;
    float4 w1 = *(const float4*)wp1;
    float4 w2 = *(const float4*)wp2;

    for (int k0 = 0; k0 < C_; k0 += 32) {
        As[mb + 0][ka] = f2bf(xa.x);
        As[mb + 1][ka] = f2bf(xa.y);
        As[mb + 2][ka] = f2bf(xa.z);
        As[mb + 3][ka] = f2bf(xa.w);
        {
            uint2 p0, p1, p2;
            p0.x = cvtpk_bf16(w0.x, w0.y); p0.y = cvtpk_bf16(w0.z, w0.w);
            p1.x = cvtpk_bf16(w1.x, w1.y); p1.y = cvtpk_bf16(w1.z, w1.w);
            p2.x = cvtpk_bf16(w2.x, w2.y); p2.y = cvtpk_bf16(w2.z, w2.w);
            *(uint2*)&Bs[ow][kb]       = p0;
            *(uint2*)&Bs[64 + ow][kb]  = p1;
            *(uint2*)&Bs[128 + ow][kb] = p2;
        }
        if (k0 + 32 < C_) {
            xa = *(const float4*)(xp + (size_t)(k0 + 32) * N_);
            w0 = *(const float4*)(wp0 + k0 + 32);
            w1 = *(const float4*)(wp1 + k0 + 32);
            w2 = *(const float4*)(wp2 + k0 + 32);
        }
        __syncthreads();
        short8 a = *(const short8*)&As[16 * mw + r][8 * g];
        __builtin_amdgcn_s_setprio(1);
        #pragma unroll
        for (int tt = 0; tt < 6; ++tt) {
            const int T = hi * 6 + tt;
            short8 bbv = *(const short8*)&Bs[T * 16 + r][8 * g];
            acc[tt] = __builtin_amdgcn_mfma_f32_16x16x32_bf16(a, bbv, acc[tt], 0, 0, 0);
        }
        __builtin_amdgcn_s_setprio(0);
        __syncthreads();
    }

    // ---- G: direct store (rows of Gt)
    #pragma unroll
    for (int u = 0; u < 2; ++u) {
        const int tt = hi ? u : (4 + u);
        const int og = hi ? (32 + u * 16 + r) : (u * 16 + r);
        const float bvv = bg[og];
        #pragma unroll
        for (int j = 0; j < 4; ++j) {
            const int loc = n0 + 16 * mw + 4 * g + j;
            Gt[((size_t)b * N_ + loc) * D_ + og] = f2bf(acc[tt][j] + bvv);
        }
    }

    ushort_t (*bb)[72] = (ushort_t(*)[72])Bs;

    // ---- F -> bb -> Ftf (fragment order), LOG2E folded. Waves 0-3 own F.
    if (hi == 0) {
        #pragma unroll
        for (int tt = 0; tt < 4; ++tt) {
            const int o = tt * 16 + r;
            const float bvv = bf[o];
            #pragma unroll
            for (int j = 0; j < 4; ++j)
                bb[16 * mw + 4 * g + j][o] = f2bf((acc[tt][j] + bvv) * LOG2E);
        }
    }
    __syncthreads();
    {
        const int f  = wv;                 // 0..7 = cc*4 + s
        const int cc = f >> 2, s = f & 3;
        short8 v = *(const short8*)&bb[32 * cc + (lane & 31)][16 * s + 8 * (lane >> 5)];
        *(short8*)&Ftf[(((size_t)b * 64 + tile) * 8 + f) * 512 + lane * 8] = v;
    }
    __syncthreads();

    // ---- H -> bb -> Vtf (fragment order). Waves 4-7 own H.
    if (hi == 1) {
        #pragma unroll
        for (int tt = 2; tt < 6; ++tt) {
            const int o = (tt - 2) * 16 + r;
            const float bvv = bh[o];
            #pragma unroll
            for (int j = 0; j < 4; ++j)
                bb[16 * mw + 4 * g + j][o] = f2bf(acc[tt][j] + bvv);
        }
    }
    __syncthreads();
    {
        const int f   = wv;                // cc*4 + sub*2 + dt
        const int cc  = f >> 2, sub = (f >> 1) & 1, dt = f & 1;
        const int h2l = lane >> 5;
        short8 v;
        #pragma unroll
        for (int e = 0; e < 8; ++e) {
            const int i = 32 * cc + 16 * sub + (e & 3) + 8 * (e >> 2) + 4 * h2l;
            v[e] = (short)bb[i][32 * dt + (lane & 31)];
        }
        *(short8*)&Vtf[(((size_t)b * 64 + tile) * 8 + f) * 512 + lane * 8] = v;
    }
}

// -------------------------------------------------------------------------
// Kernel 2: flash attention (R5 structure — best measured). 32x32x16 MFMA,
// split-K, Q=32/wave, LDS double-buffer via global_load_lds, max-free exact
// softmax, sync -> prefetch-issue -> compute loop order. Always writes
// unnormalized partials Op (bf16) + per-query denominators ml.
// -------------------------------------------------------------------------
__global__ __launch_bounds__(256, 4) void attn(
    const ushort_t* __restrict__ Ftf, const ushort_t* __restrict__ Gt,
    const ushort_t* __restrict__ Vtf,
    ushort_t* __restrict__ Op, float* __restrict__ ml, int ksplit)
{
    const int b    = blockIdx.z;
    const int part = blockIdx.y;
    const int tid  = threadIdx.x;
    const int lane = tid & 63;
    const int wave = tid >> 6;
    const int l31  = lane & 31;
    const int h2   = lane >> 5;
    const int j0   = blockIdx.x * 128 + wave * 32;
    const int NT   = (N_ / ksplit) / 64;
    const int kt0  = part * NT;

    __shared__ __align__(16) ushort_t Ks[2][4096];
    __shared__ __align__(16) ushort_t Vs[2][4096];

    const ushort_t* qrow = Gt + ((size_t)b * N_ + j0 + l31) * D_ + 8 * h2;
    const short8 qf0 = *(const short8*)(qrow);
    const short8 qf1 = *(const short8*)(qrow + 16);
    const short8 qf2 = *(const short8*)(qrow + 32);
    const short8 qf3 = *(const short8*)(qrow + 48);

    const ushort_t* Kt = Ftf + ((size_t)b * 64 + kt0) * 4096;
    const ushort_t* Vt = Vtf + ((size_t)b * 64 + kt0) * 4096;

    f32x16 oA, oB;
    #pragma unroll
    for (int q = 0; q < 16; ++q) { oA[q] = 0.f; oB[q] = 0.f; }
    float l_run = 0.f;

    // prologue: issue tile 0 DMA -> buf 0
    gl16(Kt + tid * 8,         &Ks[0][tid * 8]);
    gl16(Kt + (tid + 256) * 8, &Ks[0][(tid + 256) * 8]);
    gl16(Vt + tid * 8,         &Vs[0][tid * 8]);
    gl16(Vt + (tid + 256) * 8, &Vs[0][(tid + 256) * 8]);

    int buf = 0;
    for (int t = 0; t < NT; ++t) {
        __syncthreads();   // drains tile-t DMA (issued a full iter ago)
        if (t + 1 < NT) {
            const ushort_t* kg = Kt + (size_t)(t + 1) * 4096;
            const ushort_t* vg = Vt + (size_t)(t + 1) * 4096;
            const int nb = buf ^ 1;
            gl16(kg + tid * 8,         &Ks[nb][tid * 8]);
            gl16(kg + (tid + 256) * 8, &Ks[nb][(tid + 256) * 8]);
            gl16(vg + tid * 8,         &Vs[nb][tid * 8]);
            gl16(vg + (tid + 256) * 8, &Vs[nb][(tid + 256) * 8]);
        }
        #pragma unroll
        for (int cc = 0; cc < 2; ++cc) {
            const ushort_t* kb0 = &Ks[buf][cc * 2048];
            f32x16 sx;
            #pragma unroll
            for (int q = 0; q < 16; ++q) sx[q] = 0.f;
            __builtin_amdgcn_s_setprio(1);
            {
                const short8 k0 = *(const short8*)(kb0 + 0 * 512 + lane * 8);
                sx = __builtin_amdgcn_mfma_f32_32x32x16_bf16(k0, qf0, sx, 0, 0, 0);
                const short8 k1 = *(const short8*)(kb0 + 1 * 512 + lane * 8);
                sx = __builtin_amdgcn_mfma_f32_32x32x16_bf16(k1, qf1, sx, 0, 0, 0);
                const short8 k2 = *(const short8*)(kb0 + 2 * 512 + lane * 8);
                sx = __builtin_amdgcn_mfma_f32_32x32x16_bf16(k2, qf2, sx, 0, 0, 0);
                const short8 k3 = *(const short8*)(kb0 + 3 * 512 + lane * 8);
                sx = __builtin_amdgcn_mfma_f32_32x32x16_bf16(k3, qf3, sx, 0, 0, 0);
            }
            __builtin_amdgcn_s_setprio(0);

            // unshifted softmax numerator: p = 2^s (exact; no max tracking)
            uint32_t pw[8];
            float cs = 0.f;
            #pragma unroll
            for (int q = 0; q < 8; ++q) {
                const float pa = __builtin_amdgcn_exp2f(sx[2 * q]);
                const float pb = __builtin_amdgcn_exp2f(sx[2 * q + 1]);
                cs += pa + pb;
                pw[q] = cvtpk_bf16(pa, pb);
            }
            l_run += cs;

            union { uint32_t w[4]; short8 v; } p0u, p1u;
            p0u.w[0] = pw[0]; p0u.w[1] = pw[1]; p0u.w[2] = pw[2]; p0u.w[3] = pw[3];
            p1u.w[0] = pw[4]; p1u.w[1] = pw[5]; p1u.w[2] = pw[6]; p1u.w[3] = pw[7];

            const ushort_t* vb0 = &Vs[buf][cc * 2048];
            __builtin_amdgcn_s_setprio(1);
            {
                const short8 v00 = *(const short8*)(vb0 + 0 * 512 + lane * 8);
                oA = __builtin_amdgcn_mfma_f32_32x32x16_bf16(v00, p0u.v, oA, 0, 0, 0);
                const short8 v01 = *(const short8*)(vb0 + 1 * 512 + lane * 8);
                oB = __builtin_amdgcn_mfma_f32_32x32x16_bf16(v01, p0u.v, oB, 0, 0, 0);
                const short8 v10 = *(const short8*)(vb0 + 2 * 512 + lane * 8);
                oA = __builtin_amdgcn_mfma_f32_32x32x16_bf16(v10, p1u.v, oA, 0, 0, 0);
                const short8 v11 = *(const short8*)(vb0 + 3 * 512 + lane * 8);
                oB = __builtin_amdgcn_mfma_f32_32x32x16_bf16(v11, p1u.v, oB, 0, 0, 0);
            }
            __builtin_amdgcn_s_setprio(0);
        }
        buf ^= 1;
    }

    const float lt = l_run + __shfl_xor(l_run, 32);

    ushort_t* orow = Op + (((size_t)b * ksplit + part) * N_ + j0 + l31) * D_;
    #pragma unroll
    for (int q = 0; q < 4; ++q) {
        const int d0 = 8 * q + 4 * h2;
        uint2 ua, ub;
        ua.x = cvtpk_bf16(oA[4 * q],     oA[4 * q + 1]);
        ua.y = cvtpk_bf16(oA[4 * q + 2], oA[4 * q + 3]);
        *(uint2*)&orow[d0] = ua;
        ub.x = cvtpk_bf16(oB[4 * q],     oB[4 * q + 1]);
        ub.y = cvtpk_bf16(oB[4 * q + 2], oB[4 * q + 3]);
        *(uint2*)&orow[32 + d0] = ub;
    }
    if (h2 == 0)
        ml[((size_t)b * ksplit + part) * N_ + j0 + l31] = lt;
}

// -------------------------------------------------------------------------
// Kernel 3 (NEW, fuses reduce_attn + outproj): per (64-loc n-tile, batch):
// Phase 1: reduce KS partials -> normalized O-tile (64x64 bf16) in LDS
//   (exact math of the old reduce_attn; one bf16 rounding AFTER the sum).
// Phase 2: 8 waves x 64 co each: y = gamma*(wv @ O + bv) + x, using the
//   verified outproj MFMA pattern (A=wv rows fp32->bf16, B=O rows from LDS).
// Kills the Ot buffer and one kernel launch entirely.
// -------------------------------------------------------------------------
__global__ __launch_bounds__(512) void reduce_outproj(
    const ushort_t* __restrict__ Op, const float* __restrict__ ml,
    const float* __restrict__ wv, const float* __restrict__ bv,
    const float* __restrict__ gamma, const float* __restrict__ x,
    float* __restrict__ y, int ksplit)
{
    const int b    = blockIdx.y;
    const int n0   = blockIdx.x * 64;
    const int tid  = threadIdx.x;          // 0..511
    const int wv8  = tid >> 6;             // wave 0..7 -> co rows [wv8*64, +64)
    const int lane = tid & 63;
    const int g    = lane >> 4;
    const int r    = lane & 15;

    __shared__ ushort_t Os[64][72];        // [loc][k] normalized O tile

    // ---- phase 1: reduce partials (8 threads per loc, 8 k each)
    {
        const int loc = tid >> 3;          // 0..63
        const int k8  = (tid & 7) * 8;     // 0..56
        float L = 0.f;
        float v[8] = {0.f, 0.f, 0.f, 0.f, 0.f, 0.f, 0.f, 0.f};
        for (int p = 0; p < ksplit; ++p) {
            const size_t base = ((size_t)b * ksplit + p) * N_ + n0 + loc;
            L += ml[base];
            uint4 u = *(const uint4*)&Op[base * D_ + k8];
            v[0] += bf2f(u.x & 0xffffu); v[1] += bf2f(u.x >> 16);
            v[2] += bf2f(u.y & 0xffffu); v[3] += bf2f(u.y >> 16);
            v[4] += bf2f(u.z & 0xffffu); v[5] += bf2f(u.z >> 16);
            v[6] += bf2f(u.w & 0xffffu); v[7] += bf2f(u.w >> 16);
        }
        const float inv = 1.0f / L;
        uint4 o;
        o.x = cvtpk_bf16(v[0] * inv, v[1] * inv);
        o.y = cvtpk_bf16(v[2] * inv, v[3] * inv);
        o.z = cvtpk_bf16(v[4] * inv, v[5] * inv);
        o.w = cvtpk_bf16(v[6] * inv, v[7] * inv);
        *(uint4*)&Os[loc][k8] = o;
    }
    __syncthreads();

    // ---- phase 2: wave wv8 projects its 64 co rows against the O tile
    short8 a[4][2];
    #pragma unroll
    for (int cs = 0; cs < 4; ++cs) {
        const float* wrow = wv + (size_t)(wv8 * 64 + cs * 16 + r) * D_ + 8 * g;
        const float4 wa = *(const float4*)(wrow);
        const float4 wb = *(const float4*)(wrow + 4);
        const float4 wc = *(const float4*)(wrow + 32);
        const float4 wd = *(const float4*)(wrow + 36);
        uint32_t* a0 = (uint32_t*)&a[cs][0];
        uint32_t* a1 = (uint32_t*)&a[cs][1];
        a0[0] = cvtpk_bf16(wa.x, wa.y); a0[1] = cvtpk_bf16(wa.z, wa.w);
        a0[2] = cvtpk_bf16(wb.x, wb.y); a0[3] = cvtpk_bf16(wb.z, wb.w);
        a1[0] = cvtpk_bf16(wc.x, wc.y); a1[1] = cvtpk_bf16(wc.z, wc.w);
        a1[2] = cvtpk_bf16(wd.x, wd.y); a1[3] = cvtpk_bf16(wd.z, wd.w);
    }

    f32x4 acc[4][4];
    #pragma unroll
    for (int cs = 0; cs < 4; ++cs)
        #pragma unroll
        for (int t = 0; t < 4; ++t) acc[cs][t] = (f32x4){0.f, 0.f, 0.f, 0.f};

    #pragma unroll
    for (int t = 0; t < 4; ++t) {
        const short8 b0 = *(const short8*)&Os[16 * t + r][8 * g];
        const short8 b1 = *(const short8*)&Os[16 * t + r][32 + 8 * g];
        __builtin_amdgcn_s_setprio(1);
        #pragma unroll
        for (int cs = 0; cs < 4; ++cs) {
            acc[cs][t] = __builtin_amdgcn_mfma_f32_16x16x32_bf16(a[cs][0], b0, acc[cs][t], 0, 0, 0);
            acc[cs][t] = __builtin_amdgcn_mfma_f32_16x16x32_bf16(a[cs][1], b1, acc[cs][t], 0, 0, 0);
        }
        __builtin_amdgcn_s_setprio(0);
    }

    const float gm = *gamma;
    #pragma unroll
    for (int cs = 0; cs < 4; ++cs) {
        #pragma unroll
        for (int t = 0; t < 4; ++t) {
            #pragma unroll
            for (int j = 0; j < 4; ++j) {
                const int co = wv8 * 64 + cs * 16 + 4 * g + j;
                const int n  = n0 + 16 * t + r;
                const size_t idx = ((size_t)b * C_ + co) * N_ + n;
                y[idx] = gm * (acc[cs][t][j] + bv[co]) + x[idx];
            }
        }
    }
}

// -------------------------------------------------------------------------
extern "C" void kernel_launch(void* const* d_in, const int* in_sizes, int n_in,
                              void* d_out, int out_size, void* d_ws, size_t ws_size,
                              hipStream_t stream) {
    const float* x     = (const float*)d_in[0];
    const float* wf    = (const float*)d_in[1];
    const float* bf    = (const float*)d_in[2];
    const float* wg    = (const float*)d_in[3];
    const float* bg    = (const float*)d_in[4];
    const float* wh    = (const float*)d_in[5];
    const float* bh    = (const float*)d_in[6];
    const float* wv    = (const float*)d_in[7];
    const float* bv    = (const float*)d_in[8];
    const float* gamma = (const float*)d_in[9];
    float* y = (float*)d_out;

    const size_t plane = (size_t)B_ * N_ * D_;   // 1M elements
    ushort_t* Ftf = (ushort_t*)d_ws;             // pre-swizzled K fragments
    ushort_t* Gt  = Ftf + plane;                 // Q rows
    ushort_t* Vtf = Gt + plane;                  // pre-swizzled V fragments
    ushort_t* Op  = Vtf + plane;                 // split-K partials (bf16)

    int KS = 8;
    while (KS > 1) {
        const size_t need = 3 * plane * 2 + (size_t)KS * plane * 2
                          + (size_t)B_ * KS * N_ * sizeof(float);
        if (need <= ws_size) break;
        KS >>= 1;
    }
    float* ml = (float*)(Op + (size_t)KS * plane);

    proj_fgh<<<dim3(N_ / 64, B_), 512, 0, stream>>>(
        x, wf, bf, wg, bg, wh, bh, Ftf, Gt, Vtf);
    attn<<<dim3(N_ / 128, KS, B_), 256, 0, stream>>>(
        Ftf, Gt, Vtf, Op, ml, KS);
    reduce_outproj<<<dim3(N_ / 64, B_), 512, 0, stream>>>(
        Op, ml, wv, bv, gamma, x, y, KS);
}

// Round 10
// 59.439 us; speedup vs baseline: 1.1346x; 1.0113x over previous
//
#include <hip/hip_runtime.h>
#include <stdint.h>

#define B_ 4
#define C_ 512
#define N_ 4096
#define D_ 64
#define LOG2E 1.4426950408889634f

typedef __attribute__((ext_vector_type(8))) short short8;
typedef __attribute__((ext_vector_type(4))) float f32x4;
typedef __attribute__((ext_vector_type(16))) float f32x16;
typedef unsigned short ushort_t;

static __device__ __forceinline__ ushort_t f2bf(float f) {
    union { float f; uint32_t u; } v; v.f = f;
    uint32_t u = v.u;
    uint32_t r = u + 0x7FFFu + ((u >> 16) & 1u);
    return (ushort_t)(r >> 16);
}
static __device__ __forceinline__ float bf2f(uint32_t u) {
    union { uint32_t u; float f; } v; v.u = u << 16;
    return v.f;
}
static __device__ __forceinline__ uint32_t cvtpk_bf16(float lo, float hi) {
    uint32_t r;
    asm("v_cvt_pk_bf16_f32 %0, %1, %2" : "=v"(r) : "v"(lo), "v"(hi));
    return r;
}
// async global->LDS, 16B per lane. LDS dst must be wave-uniform base + lane*16.
static __device__ __forceinline__ void gl16(const ushort_t* g, ushort_t* l) {
    __builtin_amdgcn_global_load_lds(
        (const __attribute__((address_space(1))) void*)g,
        (__attribute__((address_space(3))) void*)l, 16, 0, 0);
}

// -------------------------------------------------------------------------
// Kernel 1: merged F/G/H projections, 32-LOC TILES (grid 512 = 2 blocks/CU,
// 4 waves/SIMD — doubles latency hiding vs R9's 1 block/CU).
// 512 thr = 8 waves: mw = wv&1 (m-tile of 16 locs), hi = wv>>1 (o-group);
// wave handles o-tiles T = tt*4 + hi, tt=0(F),1(G),2(H) — uniform epilogue.
// F gets LOG2E folded; F -> Ftf, H -> Vtf in attn-fragment order (the
// verified formulas with block-level cc = blockIdx.x&1).
// -------------------------------------------------------------------------
__global__ __launch_bounds__(512) void proj_fgh(
    const float* __restrict__ x,
    const float* __restrict__ wf, const float* __restrict__ bf,
    const float* __restrict__ wg, const float* __restrict__ bg,
    const float* __restrict__ wh, const float* __restrict__ bh,
    ushort_t* __restrict__ Ftf, ushort_t* __restrict__ Gt,
    ushort_t* __restrict__ Vtf)
{
    const int b    = blockIdx.y;
    const int nb   = blockIdx.x;           // 0..127
    const int tile = nb >> 1;              // 64-key tile index
    const int cc   = nb & 1;               // which 32-half of the tile
    const int n0   = nb * 32;
    const int tid  = threadIdx.x;          // 0..511
    const int wv   = tid >> 6;             // 0..7
    const int mw   = wv & 1;               // m-tile (16 locs)
    const int hi   = wv >> 1;              // o-group 0..3
    const int lane = tid & 63;
    const int g    = lane >> 4;
    const int r    = lane & 15;

    __shared__ ushort_t As[32][40];        // [loc][k]
    __shared__ ushort_t Bs[192][40];       // [o][k]

    f32x4 acc[3];
    #pragma unroll
    for (int t = 0; t < 3; ++t) acc[t] = (f32x4){0.f, 0.f, 0.f, 0.f};

    const int ka = tid >> 4;               // 0..31 (k row)
    const int mb = (tid & 15) * 2;         // 0..30 (2 locs)
    const int ow = tid >> 3;               // 0..63 (o row within group)
    const int kb = (tid & 7) * 4;          // 0..28

    const float* xp  = x  + ((size_t)b * C_ + ka) * N_ + n0 + mb;
    const float* wp0 = wf + (size_t)ow * C_ + kb;
    const float* wp1 = wg + (size_t)ow * C_ + kb;
    const float* wp2 = wh + (size_t)ow * C_ + kb;

    // prefetch chunk 0 (register double-buffer)
    float2 xa = *(const float2*)xp;
    float4 w0 = *(const float4*)wp0;
    float4 w1 = *(const float4*)wp1;
    float4 w2 = *(const float4*)wp2;

    for (int k0 = 0; k0 < C_; k0 += 32) {
        As[mb + 0][ka] = f2bf(xa.x);
        As[mb + 1][ka] = f2bf(xa.y);
        {
            uint2 p0, p1, p2;
            p0.x = cvtpk_bf16(w0.x, w0.y); p0.y = cvtpk_bf16(w0.z, w0.w);
            p1.x = cvtpk_bf16(w1.x, w1.y); p1.y = cvtpk_bf16(w1.z, w1.w);
            p2.x = cvtpk_bf16(w2.x, w2.y); p2.y = cvtpk_bf16(w2.z, w2.w);
            *(uint2*)&Bs[ow][kb]       = p0;
            *(uint2*)&Bs[64 + ow][kb]  = p1;
            *(uint2*)&Bs[128 + ow][kb] = p2;
        }
        if (k0 + 32 < C_) {
            xa = *(const float2*)(xp + (size_t)(k0 + 32) * N_);
            w0 = *(const float4*)(wp0 + k0 + 32);
            w1 = *(const float4*)(wp1 + k0 + 32);
            w2 = *(const float4*)(wp2 + k0 + 32);
        }
        __syncthreads();
        short8 a = *(const short8*)&As[16 * mw + r][8 * g];
        __builtin_amdgcn_s_setprio(1);
        #pragma unroll
        for (int tt = 0; tt < 3; ++tt) {
            const int T = tt * 4 + hi;
            short8 bbv = *(const short8*)&Bs[T * 16 + r][8 * g];
            acc[tt] = __builtin_amdgcn_mfma_f32_16x16x32_bf16(a, bbv, acc[tt], 0, 0, 0);
        }
        __builtin_amdgcn_s_setprio(0);
        __syncthreads();
    }

    // ---- G (tt=1): direct store, o = hi*16 + r
    {
        const int og = hi * 16 + r;
        const float bvv = bg[og];
        #pragma unroll
        for (int j = 0; j < 4; ++j) {
            const int loc = n0 + 16 * mw + 4 * g + j;
            Gt[((size_t)b * N_ + loc) * D_ + og] = f2bf(acc[1][j] + bvv);
        }
    }

    // ---- bounce buffers alias Bs (dead after k-loop; last barrier of the
    // k-loop guarantees all Bs reads completed)
    ushort_t (*bbF)[72] = (ushort_t(*)[72])&Bs[0][0];
    ushort_t (*bbH)[72] = (ushort_t(*)[72])(&Bs[0][0] + 32 * 72);

    // F (tt=0): o = hi*16 + r, LOG2E folded
    {
        const int o = hi * 16 + r;
        const float bvv = bf[o];
        #pragma unroll
        for (int j = 0; j < 4; ++j)
            bbF[16 * mw + 4 * g + j][o] = f2bf((acc[0][j] + bvv) * LOG2E);
    }
    // H (tt=2): o = hi*16 + r
    {
        const int o = hi * 16 + r;
        const float bvv = bh[o];
        #pragma unroll
        for (int j = 0; j < 4; ++j)
            bbH[16 * mw + 4 * g + j][o] = f2bf(acc[2][j] + bvv);
    }
    __syncthreads();

    // ---- fragment stores: threads 0-255 -> K frags, 256-511 -> V frags
    if (tid < 256) {
        const int s = (tid >> 6) & 3;          // d-slab
        const int l = tid & 63;
        short8 v = *(const short8*)&bbF[l & 31][16 * s + 8 * (l >> 5)];
        const int f = cc * 4 + s;
        *(short8*)&Ftf[(((size_t)b * 64 + tile) * 8 + f) * 512 + l * 8] = v;
    } else {
        const int u   = tid & 255;
        const int fi  = u >> 6;                // sub*2 + dt
        const int sub = fi >> 1, dt = fi & 1;
        const int l   = u & 63;
        const int h2l = l >> 5;
        short8 v;
        #pragma unroll
        for (int e = 0; e < 8; ++e) {
            const int i = 16 * sub + (e & 3) + 8 * (e >> 2) + 4 * h2l;
            v[e] = (short)bbH[i][32 * dt + (l & 31)];
        }
        const int f = cc * 4 + sub * 2 + dt;
        *(short8*)&Vtf[(((size_t)b * 64 + tile) * 8 + f) * 512 + l * 8] = v;
    }
}

// -------------------------------------------------------------------------
// Kernel 2: flash attention (R5/R9 structure — best measured, unchanged).
// 32x32x16 MFMA, split-K, Q=32/wave, LDS double-buffer via global_load_lds,
// max-free exact softmax, sync -> prefetch-issue -> compute loop order.
// Writes unnormalized partials Op (bf16) + per-query denominators ml.
// -------------------------------------------------------------------------
__global__ __launch_bounds__(256, 4) void attn(
    const ushort_t* __restrict__ Ftf, const ushort_t* __restrict__ Gt,
    const ushort_t* __restrict__ Vtf,
    ushort_t* __restrict__ Op, float* __restrict__ ml, int ksplit)
{
    const int b    = blockIdx.z;
    const int part = blockIdx.y;
    const int tid  = threadIdx.x;
    const int lane = tid & 63;
    const int wave = tid >> 6;
    const int l31  = lane & 31;
    const int h2   = lane >> 5;
    const int j0   = blockIdx.x * 128 + wave * 32;
    const int NT   = (N_ / ksplit) / 64;
    const int kt0  = part * NT;

    __shared__ __align__(16) ushort_t Ks[2][4096];
    __shared__ __align__(16) ushort_t Vs[2][4096];

    const ushort_t* qrow = Gt + ((size_t)b * N_ + j0 + l31) * D_ + 8 * h2;
    const short8 qf0 = *(const short8*)(qrow);
    const short8 qf1 = *(const short8*)(qrow + 16);
    const short8 qf2 = *(const short8*)(qrow + 32);
    const short8 qf3 = *(const short8*)(qrow + 48);

    const ushort_t* Kt = Ftf + ((size_t)b * 64 + kt0) * 4096;
    const ushort_t* Vt = Vtf + ((size_t)b * 64 + kt0) * 4096;

    f32x16 oA, oB;
    #pragma unroll
    for (int q = 0; q < 16; ++q) { oA[q] = 0.f; oB[q] = 0.f; }
    float l_run = 0.f;

    gl16(Kt + tid * 8,         &Ks[0][tid * 8]);
    gl16(Kt + (tid + 256) * 8, &Ks[0][(tid + 256) * 8]);
    gl16(Vt + tid * 8,         &Vs[0][tid * 8]);
    gl16(Vt + (tid + 256) * 8, &Vs[0][(tid + 256) * 8]);

    int buf = 0;
    for (int t = 0; t < NT; ++t) {
        __syncthreads();   // drains tile-t DMA (issued a full iter ago)
        if (t + 1 < NT) {
            const ushort_t* kg = Kt + (size_t)(t + 1) * 4096;
            const ushort_t* vg = Vt + (size_t)(t + 1) * 4096;
            const int nb = buf ^ 1;
            gl16(kg + tid * 8,         &Ks[nb][tid * 8]);
            gl16(kg + (tid + 256) * 8, &Ks[nb][(tid + 256) * 8]);
            gl16(vg + tid * 8,         &Vs[nb][tid * 8]);
            gl16(vg + (tid + 256) * 8, &Vs[nb][(tid + 256) * 8]);
        }
        #pragma unroll
        for (int cc = 0; cc < 2; ++cc) {
            const ushort_t* kb0 = &Ks[buf][cc * 2048];
            f32x16 sx;
            #pragma unroll
            for (int q = 0; q < 16; ++q) sx[q] = 0.f;
            __builtin_amdgcn_s_setprio(1);
            {
                const short8 k0 = *(const short8*)(kb0 + 0 * 512 + lane * 8);
                sx = __builtin_amdgcn_mfma_f32_32x32x16_bf16(k0, qf0, sx, 0, 0, 0);
                const short8 k1 = *(const short8*)(kb0 + 1 * 512 + lane * 8);
                sx = __builtin_amdgcn_mfma_f32_32x32x16_bf16(k1, qf1, sx, 0, 0, 0);
                const short8 k2 = *(const short8*)(kb0 + 2 * 512 + lane * 8);
                sx = __builtin_amdgcn_mfma_f32_32x32x16_bf16(k2, qf2, sx, 0, 0, 0);
                const short8 k3 = *(const short8*)(kb0 + 3 * 512 + lane * 8);
                sx = __builtin_amdgcn_mfma_f32_32x32x16_bf16(k3, qf3, sx, 0, 0, 0);
            }
            __builtin_amdgcn_s_setprio(0);

            uint32_t pw[8];
            float cs = 0.f;
            #pragma unroll
            for (int q = 0; q < 8; ++q) {
                const float pa = __builtin_amdgcn_exp2f(sx[2 * q]);
                const float pb = __builtin_amdgcn_exp2f(sx[2 * q + 1]);
                cs += pa + pb;
                pw[q] = cvtpk_bf16(pa, pb);
            }
            l_run += cs;

            union { uint32_t w[4]; short8 v; } p0u, p1u;
            p0u.w[0] = pw[0]; p0u.w[1] = pw[1]; p0u.w[2] = pw[2]; p0u.w[3] = pw[3];
            p1u.w[0] = pw[4]; p1u.w[1] = pw[5]; p1u.w[2] = pw[6]; p1u.w[3] = pw[7];

            const ushort_t* vb0 = &Vs[buf][cc * 2048];
            __builtin_amdgcn_s_setprio(1);
            {
                const short8 v00 = *(const short8*)(vb0 + 0 * 512 + lane * 8);
                oA = __builtin_amdgcn_mfma_f32_32x32x16_bf16(v00, p0u.v, oA, 0, 0, 0);
                const short8 v01 = *(const short8*)(vb0 + 1 * 512 + lane * 8);
                oB = __builtin_amdgcn_mfma_f32_32x32x16_bf16(v01, p0u.v, oB, 0, 0, 0);
                const short8 v10 = *(const short8*)(vb0 + 2 * 512 + lane * 8);
                oA = __builtin_amdgcn_mfma_f32_32x32x16_bf16(v10, p1u.v, oA, 0, 0, 0);
                const short8 v11 = *(const short8*)(vb0 + 3 * 512 + lane * 8);
                oB = __builtin_amdgcn_mfma_f32_32x32x16_bf16(v11, p1u.v, oB, 0, 0, 0);
            }
            __builtin_amdgcn_s_setprio(0);
        }
        buf ^= 1;
    }

    const float lt = l_run + __shfl_xor(l_run, 32);

    ushort_t* orow = Op + (((size_t)b * ksplit + part) * N_ + j0 + l31) * D_;
    #pragma unroll
    for (int q = 0; q < 4; ++q) {
        const int d0 = 8 * q + 4 * h2;
        uint2 ua, ub;
        ua.x = cvtpk_bf16(oA[4 * q],     oA[4 * q + 1]);
        ua.y = cvtpk_bf16(oA[4 * q + 2], oA[4 * q + 3]);
        *(uint2*)&orow[d0] = ua;
        ub.x = cvtpk_bf16(oB[4 * q],     oB[4 * q + 1]);
        ub.y = cvtpk_bf16(oB[4 * q + 2], oB[4 * q + 3]);
        *(uint2*)&orow[32 + d0] = ub;
    }
    if (h2 == 0)
        ml[((size_t)b * ksplit + part) * N_ + j0 + l31] = lt;
}

// -------------------------------------------------------------------------
// Kernel 3: fused reduce + outproj (verified R9, unchanged).
// -------------------------------------------------------------------------
__global__ __launch_bounds__(512) void reduce_outproj(
    const ushort_t* __restrict__ Op, const float* __restrict__ ml,
    const float* __restrict__ wv, const float* __restrict__ bv,
    const float* __restrict__ gamma, const float* __restrict__ x,
    float* __restrict__ y, int ksplit)
{
    const int b    = blockIdx.y;
    const int n0   = blockIdx.x * 64;
    const int tid  = threadIdx.x;          // 0..511
    const int wv8  = tid >> 6;             // wave 0..7 -> co rows [wv8*64, +64)
    const int lane = tid & 63;
    const int g    = lane >> 4;
    const int r    = lane & 15;

    __shared__ ushort_t Os[64][72];        // [loc][k] normalized O tile

    {
        const int loc = tid >> 3;          // 0..63
        const int k8  = (tid & 7) * 8;     // 0..56
        float L = 0.f;
        float v[8] = {0.f, 0.f, 0.f, 0.f, 0.f, 0.f, 0.f, 0.f};
        for (int p = 0; p < ksplit; ++p) {
            const size_t base = ((size_t)b * ksplit + p) * N_ + n0 + loc;
            L += ml[base];
            uint4 u = *(const uint4*)&Op[base * D_ + k8];
            v[0] += bf2f(u.x & 0xffffu); v[1] += bf2f(u.x >> 16);
            v[2] += bf2f(u.y & 0xffffu); v[3] += bf2f(u.y >> 16);
            v[4] += bf2f(u.z & 0xffffu); v[5] += bf2f(u.z >> 16);
            v[6] += bf2f(u.w & 0xffffu); v[7] += bf2f(u.w >> 16);
        }
        const float inv = 1.0f / L;
        uint4 o;
        o.x = cvtpk_bf16(v[0] * inv, v[1] * inv);
        o.y = cvtpk_bf16(v[2] * inv, v[3] * inv);
        o.z = cvtpk_bf16(v[4] * inv, v[5] * inv);
        o.w = cvtpk_bf16(v[6] * inv, v[7] * inv);
        *(uint4*)&Os[loc][k8] = o;
    }
    __syncthreads();

    short8 a[4][2];
    #pragma unroll
    for (int cs = 0; cs < 4; ++cs) {
        const float* wrow = wv + (size_t)(wv8 * 64 + cs * 16 + r) * D_ + 8 * g;
        const float4 wa = *(const float4*)(wrow);
        const float4 wb = *(const float4*)(wrow + 4);
        const float4 wc = *(const float4*)(wrow + 32);
        const float4 wd = *(const float4*)(wrow + 36);
        uint32_t* a0 = (uint32_t*)&a[cs][0];
        uint32_t* a1 = (uint32_t*)&a[cs][1];
        a0[0] = cvtpk_bf16(wa.x, wa.y); a0[1] = cvtpk_bf16(wa.z, wa.w);
        a0[2] = cvtpk_bf16(wb.x, wb.y); a0[3] = cvtpk_bf16(wb.z, wb.w);
        a1[0] = cvtpk_bf16(wc.x, wc.y); a1[1] = cvtpk_bf16(wc.z, wc.w);
        a1[2] = cvtpk_bf16(wd.x, wd.y); a1[3] = cvtpk_bf16(wd.z, wd.w);
    }

    f32x4 acc[4][4];
    #pragma unroll
    for (int cs = 0; cs < 4; ++cs)
        #pragma unroll
        for (int t = 0; t < 4; ++t) acc[cs][t] = (f32x4){0.f, 0.f, 0.f, 0.f};

    #pragma unroll
    for (int t = 0; t < 4; ++t) {
        const short8 b0 = *(const short8*)&Os[16 * t + r][8 * g];
        const short8 b1 = *(const short8*)&Os[16 * t + r][32 + 8 * g];
        __builtin_amdgcn_s_setprio(1);
        #pragma unroll
        for (int cs = 0; cs < 4; ++cs) {
            acc[cs][t] = __builtin_amdgcn_mfma_f32_16x16x32_bf16(a[cs][0], b0, acc[cs][t], 0, 0, 0);
            acc[cs][t] = __builtin_amdgcn_mfma_f32_16x16x32_bf16(a[cs][1], b1, acc[cs][t], 0, 0, 0);
        }
        __builtin_amdgcn_s_setprio(0);
    }

    const float gm = *gamma;
    #pragma unroll
    for (int cs = 0; cs < 4; ++cs) {
        #pragma unroll
        for (int t = 0; t < 4; ++t) {
            #pragma unroll
            for (int j = 0; j < 4; ++j) {
                const int co = wv8 * 64 + cs * 16 + 4 * g + j;
                const int n  = n0 + 16 * t + r;
                const size_t idx = ((size_t)b * C_ + co) * N_ + n;
                y[idx] = gm * (acc[cs][t][j] + bv[co]) + x[idx];
            }
        }
    }
}

// -------------------------------------------------------------------------
extern "C" void kernel_launch(void* const* d_in, const int* in_sizes, int n_in,
                              void* d_out, int out_size, void* d_ws, size_t ws_size,
                              hipStream_t stream) {
    const float* x     = (const float*)d_in[0];
    const float* wf    = (const float*)d_in[1];
    const float* bf    = (const float*)d_in[2];
    const float* wg    = (const float*)d_in[3];
    const float* bg    = (const float*)d_in[4];
    const float* wh    = (const float*)d_in[5];
    const float* bh    = (const float*)d_in[6];
    const float* wv    = (const float*)d_in[7];
    const float* bv    = (const float*)d_in[8];
    const float* gamma = (const float*)d_in[9];
    float* y = (float*)d_out;

    const size_t plane = (size_t)B_ * N_ * D_;   // 1M elements
    ushort_t* Ftf = (ushort_t*)d_ws;             // pre-swizzled K fragments
    ushort_t* Gt  = Ftf + plane;                 // Q rows
    ushort_t* Vtf = Gt + plane;                  // pre-swizzled V fragments
    ushort_t* Op  = Vtf + plane;                 // split-K partials (bf16)

    int KS = 8;
    while (KS > 1) {
        const size_t need = 3 * plane * 2 + (size_t)KS * plane * 2
                          + (size_t)B_ * KS * N_ * sizeof(float);
        if (need <= ws_size) break;
        KS >>= 1;
    }
    float* ml = (float*)(Op + (size_t)KS * plane);

    proj_fgh<<<dim3(N_ / 32, B_), 512, 0, stream>>>(
        x, wf, bf, wg, bg, wh, bh, Ftf, Gt, Vtf);
    attn<<<dim3(N_ / 128, KS, B_), 256, 0, stream>>>(
        Ftf, Gt, Vtf, Op, ml, KS);
    reduce_outproj<<<dim3(N_ / 64, B_), 512, 0, stream>>>(
        Op, ml, wv, bv, gamma, x, y, KS);
}

// Round 11
// 58.771 us; speedup vs baseline: 1.1475x; 1.0114x over previous
//
#include <hip/hip_runtime.h>
#include <stdint.h>

#define B_ 4
#define C_ 512
#define N_ 4096
#define D_ 64
#define LOG2E 1.4426950408889634f

typedef __attribute__((ext_vector_type(8))) short short8;
typedef __attribute__((ext_vector_type(4))) float f32x4;
typedef __attribute__((ext_vector_type(16))) float f32x16;
typedef unsigned short ushort_t;

static __device__ __forceinline__ ushort_t f2bf(float f) {
    union { float f; uint32_t u; } v; v.f = f;
    uint32_t u = v.u;
    uint32_t r = u + 0x7FFFu + ((u >> 16) & 1u);
    return (ushort_t)(r >> 16);
}
static __device__ __forceinline__ float bf2f(uint32_t u) {
    union { uint32_t u; float f; } v; v.u = u << 16;
    return v.f;
}
static __device__ __forceinline__ uint32_t cvtpk_bf16(float lo, float hi) {
    uint32_t r;
    asm("v_cvt_pk_bf16_f32 %0, %1, %2" : "=v"(r) : "v"(lo), "v"(hi));
    return r;
}
// async global->LDS, 16B per lane. LDS dst must be wave-uniform base + lane*16.
static __device__ __forceinline__ void gl16(const ushort_t* g, ushort_t* l) {
    __builtin_amdgcn_global_load_lds(
        (const __attribute__((address_space(1))) void*)g,
        (__attribute__((address_space(3))) void*)l, 16, 0, 0);
}

// -------------------------------------------------------------------------
// Kernel 1: merged F/G/H projections, 32-loc tiles (R10 config, verified).
// -------------------------------------------------------------------------
__global__ __launch_bounds__(512) void proj_fgh(
    const float* __restrict__ x,
    const float* __restrict__ wf, const float* __restrict__ bf,
    const float* __restrict__ wg, const float* __restrict__ bg,
    const float* __restrict__ wh, const float* __restrict__ bh,
    ushort_t* __restrict__ Ftf, ushort_t* __restrict__ Gt,
    ushort_t* __restrict__ Vtf)
{
    const int b    = blockIdx.y;
    const int nb   = blockIdx.x;           // 0..127
    const int tile = nb >> 1;              // 64-key tile index
    const int cc   = nb & 1;               // which 32-half of the tile
    const int n0   = nb * 32;
    const int tid  = threadIdx.x;          // 0..511
    const int wv   = tid >> 6;             // 0..7
    const int mw   = wv & 1;               // m-tile (16 locs)
    const int hi   = wv >> 1;              // o-group 0..3
    const int lane = tid & 63;
    const int g    = lane >> 4;
    const int r    = lane & 15;

    __shared__ ushort_t As[32][40];        // [loc][k]
    __shared__ ushort_t Bs[192][40];       // [o][k]

    f32x4 acc[3];
    #pragma unroll
    for (int t = 0; t < 3; ++t) acc[t] = (f32x4){0.f, 0.f, 0.f, 0.f};

    const int ka = tid >> 4;               // 0..31 (k row)
    const int mb = (tid & 15) * 2;         // 0..30 (2 locs)
    const int ow = tid >> 3;               // 0..63 (o row within group)
    const int kb = (tid & 7) * 4;          // 0..28

    const float* xp  = x  + ((size_t)b * C_ + ka) * N_ + n0 + mb;
    const float* wp0 = wf + (size_t)ow * C_ + kb;
    const float* wp1 = wg + (size_t)ow * C_ + kb;
    const float* wp2 = wh + (size_t)ow * C_ + kb;

    float2 xa = *(const float2*)xp;
    float4 w0 = *(const float4*)wp0;
    float4 w1 = *(const float4*)wp1;
    float4 w2 = *(const float4*)wp2;

    for (int k0 = 0; k0 < C_; k0 += 32) {
        As[mb + 0][ka] = f2bf(xa.x);
        As[mb + 1][ka] = f2bf(xa.y);
        {
            uint2 p0, p1, p2;
            p0.x = cvtpk_bf16(w0.x, w0.y); p0.y = cvtpk_bf16(w0.z, w0.w);
            p1.x = cvtpk_bf16(w1.x, w1.y); p1.y = cvtpk_bf16(w1.z, w1.w);
            p2.x = cvtpk_bf16(w2.x, w2.y); p2.y = cvtpk_bf16(w2.z, w2.w);
            *(uint2*)&Bs[ow][kb]       = p0;
            *(uint2*)&Bs[64 + ow][kb]  = p1;
            *(uint2*)&Bs[128 + ow][kb] = p2;
        }
        if (k0 + 32 < C_) {
            xa = *(const float2*)(xp + (size_t)(k0 + 32) * N_);
            w0 = *(const float4*)(wp0 + k0 + 32);
            w1 = *(const float4*)(wp1 + k0 + 32);
            w2 = *(const float4*)(wp2 + k0 + 32);
        }
        __syncthreads();
        short8 a = *(const short8*)&As[16 * mw + r][8 * g];
        __builtin_amdgcn_s_setprio(1);
        #pragma unroll
        for (int tt = 0; tt < 3; ++tt) {
            const int T = tt * 4 + hi;
            short8 bbv = *(const short8*)&Bs[T * 16 + r][8 * g];
            acc[tt] = __builtin_amdgcn_mfma_f32_16x16x32_bf16(a, bbv, acc[tt], 0, 0, 0);
        }
        __builtin_amdgcn_s_setprio(0);
        __syncthreads();
    }

    // ---- G (tt=1): direct store, o = hi*16 + r
    {
        const int og = hi * 16 + r;
        const float bvv = bg[og];
        #pragma unroll
        for (int j = 0; j < 4; ++j) {
            const int loc = n0 + 16 * mw + 4 * g + j;
            Gt[((size_t)b * N_ + loc) * D_ + og] = f2bf(acc[1][j] + bvv);
        }
    }

    ushort_t (*bbF)[72] = (ushort_t(*)[72])&Bs[0][0];
    ushort_t (*bbH)[72] = (ushort_t(*)[72])(&Bs[0][0] + 32 * 72);

    {
        const int o = hi * 16 + r;
        const float bvv = bf[o];
        #pragma unroll
        for (int j = 0; j < 4; ++j)
            bbF[16 * mw + 4 * g + j][o] = f2bf((acc[0][j] + bvv) * LOG2E);
    }
    {
        const int o = hi * 16 + r;
        const float bvv = bh[o];
        #pragma unroll
        for (int j = 0; j < 4; ++j)
            bbH[16 * mw + 4 * g + j][o] = f2bf(acc[2][j] + bvv);
    }
    __syncthreads();

    if (tid < 256) {
        const int s = (tid >> 6) & 3;          // d-slab
        const int l = tid & 63;
        short8 v = *(const short8*)&bbF[l & 31][16 * s + 8 * (l >> 5)];
        const int f = cc * 4 + s;
        *(short8*)&Ftf[(((size_t)b * 64 + tile) * 8 + f) * 512 + l * 8] = v;
    } else {
        const int u   = tid & 255;
        const int fi  = u >> 6;                // sub*2 + dt
        const int sub = fi >> 1, dt = fi & 1;
        const int l   = u & 63;
        const int h2l = l >> 5;
        short8 v;
        #pragma unroll
        for (int e = 0; e < 8; ++e) {
            const int i = 16 * sub + (e & 3) + 8 * (e >> 2) + 4 * h2l;
            v[e] = (short)bbH[i][32 * dt + (l & 31)];
        }
        const int f = cc * 4 + sub * 2 + dt;
        *(short8*)&Vtf[(((size_t)b * 64 + tile) * 8 + f) * 512 + l * 8] = v;
    }
}

// -------------------------------------------------------------------------
// Kernel 2: flash attention — R5/R9 data structure, but the two independent
// 32-key sub-chunks of each tile are SOFTWARE-PIPELINED within the wave:
//   S(0) -> issue S(1) MFMAs -> SM(0) on VALU/trans (overlaps S(1)) ->
//   PV(0) on matrix pipe -> SM(1) (overlaps PV(0)) -> PV(1)
// Shortens the per-tile serial chain; identical math and layouts.
// -------------------------------------------------------------------------
__global__ __launch_bounds__(256, 4) void attn(
    const ushort_t* __restrict__ Ftf, const ushort_t* __restrict__ Gt,
    const ushort_t* __restrict__ Vtf,
    ushort_t* __restrict__ Op, float* __restrict__ ml, int ksplit)
{
    const int b    = blockIdx.z;
    const int part = blockIdx.y;
    const int tid  = threadIdx.x;
    const int lane = tid & 63;
    const int wave = tid >> 6;
    const int l31  = lane & 31;
    const int h2   = lane >> 5;
    const int j0   = blockIdx.x * 128 + wave * 32;
    const int NT   = (N_ / ksplit) / 64;
    const int kt0  = part * NT;

    __shared__ __align__(16) ushort_t Ks[2][4096];
    __shared__ __align__(16) ushort_t Vs[2][4096];

    const ushort_t* qrow = Gt + ((size_t)b * N_ + j0 + l31) * D_ + 8 * h2;
    const short8 qf0 = *(const short8*)(qrow);
    const short8 qf1 = *(const short8*)(qrow + 16);
    const short8 qf2 = *(const short8*)(qrow + 32);
    const short8 qf3 = *(const short8*)(qrow + 48);

    const ushort_t* Kt = Ftf + ((size_t)b * 64 + kt0) * 4096;
    const ushort_t* Vt = Vtf + ((size_t)b * 64 + kt0) * 4096;

    f32x16 oA, oB;
    #pragma unroll
    for (int q = 0; q < 16; ++q) { oA[q] = 0.f; oB[q] = 0.f; }
    float l_run = 0.f;

    gl16(Kt + tid * 8,         &Ks[0][tid * 8]);
    gl16(Kt + (tid + 256) * 8, &Ks[0][(tid + 256) * 8]);
    gl16(Vt + tid * 8,         &Vs[0][tid * 8]);
    gl16(Vt + (tid + 256) * 8, &Vs[0][(tid + 256) * 8]);

    int buf = 0;
    for (int t = 0; t < NT; ++t) {
        __syncthreads();   // drains tile-t DMA (issued a full iter ago)
        if (t + 1 < NT) {
            const ushort_t* kg = Kt + (size_t)(t + 1) * 4096;
            const ushort_t* vg = Vt + (size_t)(t + 1) * 4096;
            const int nb = buf ^ 1;
            gl16(kg + tid * 8,         &Ks[nb][tid * 8]);
            gl16(kg + (tid + 256) * 8, &Ks[nb][(tid + 256) * 8]);
            gl16(vg + tid * 8,         &Vs[nb][tid * 8]);
            gl16(vg + (tid + 256) * 8, &Vs[nb][(tid + 256) * 8]);
        }

        const ushort_t* kb0 = &Ks[buf][0];
        const ushort_t* kb1 = &Ks[buf][2048];
        const ushort_t* vb0 = &Vs[buf][0];
        const ushort_t* vb1 = &Vs[buf][2048];

        // ---- S(0) then S(1): both score MFMAs issued before any softmax
        f32x16 sx0, sx1;
        #pragma unroll
        for (int q = 0; q < 16; ++q) { sx0[q] = 0.f; sx1[q] = 0.f; }
        __builtin_amdgcn_s_setprio(1);
        {
            const short8 ka0 = *(const short8*)(kb0 + 0 * 512 + lane * 8);
            sx0 = __builtin_amdgcn_mfma_f32_32x32x16_bf16(ka0, qf0, sx0, 0, 0, 0);
            const short8 ka1 = *(const short8*)(kb0 + 1 * 512 + lane * 8);
            sx0 = __builtin_amdgcn_mfma_f32_32x32x16_bf16(ka1, qf1, sx0, 0, 0, 0);
            const short8 ka2 = *(const short8*)(kb0 + 2 * 512 + lane * 8);
            sx0 = __builtin_amdgcn_mfma_f32_32x32x16_bf16(ka2, qf2, sx0, 0, 0, 0);
            const short8 ka3 = *(const short8*)(kb0 + 3 * 512 + lane * 8);
            sx0 = __builtin_amdgcn_mfma_f32_32x32x16_bf16(ka3, qf3, sx0, 0, 0, 0);
            const short8 kb0f = *(const short8*)(kb1 + 0 * 512 + lane * 8);
            sx1 = __builtin_amdgcn_mfma_f32_32x32x16_bf16(kb0f, qf0, sx1, 0, 0, 0);
            const short8 kb1f = *(const short8*)(kb1 + 1 * 512 + lane * 8);
            sx1 = __builtin_amdgcn_mfma_f32_32x32x16_bf16(kb1f, qf1, sx1, 0, 0, 0);
            const short8 kb2f = *(const short8*)(kb1 + 2 * 512 + lane * 8);
            sx1 = __builtin_amdgcn_mfma_f32_32x32x16_bf16(kb2f, qf2, sx1, 0, 0, 0);
            const short8 kb3f = *(const short8*)(kb1 + 3 * 512 + lane * 8);
            sx1 = __builtin_amdgcn_mfma_f32_32x32x16_bf16(kb3f, qf3, sx1, 0, 0, 0);
        }
        __builtin_amdgcn_s_setprio(0);

        // ---- SM(0): overlaps S(1) MFMAs still in the matrix pipe
        float cs0 = 0.f;
        union { uint32_t w[4]; short8 v; } p00, p01;
        {
            uint32_t pw[8];
            #pragma unroll
            for (int q = 0; q < 8; ++q) {
                const float pa = __builtin_amdgcn_exp2f(sx0[2 * q]);
                const float pb = __builtin_amdgcn_exp2f(sx0[2 * q + 1]);
                cs0 += pa + pb;
                pw[q] = cvtpk_bf16(pa, pb);
            }
            p00.w[0] = pw[0]; p00.w[1] = pw[1]; p00.w[2] = pw[2]; p00.w[3] = pw[3];
            p01.w[0] = pw[4]; p01.w[1] = pw[5]; p01.w[2] = pw[6]; p01.w[3] = pw[7];
        }

        // ---- PV(0): matrix pipe; SM(1) below overlaps these MFMAs
        __builtin_amdgcn_s_setprio(1);
        {
            const short8 v00 = *(const short8*)(vb0 + 0 * 512 + lane * 8);
            oA = __builtin_amdgcn_mfma_f32_32x32x16_bf16(v00, p00.v, oA, 0, 0, 0);
            const short8 v01 = *(const short8*)(vb0 + 1 * 512 + lane * 8);
            oB = __builtin_amdgcn_mfma_f32_32x32x16_bf16(v01, p00.v, oB, 0, 0, 0);
            const short8 v10 = *(const short8*)(vb0 + 2 * 512 + lane * 8);
            oA = __builtin_amdgcn_mfma_f32_32x32x16_bf16(v10, p01.v, oA, 0, 0, 0);
            const short8 v11 = *(const short8*)(vb0 + 3 * 512 + lane * 8);
            oB = __builtin_amdgcn_mfma_f32_32x32x16_bf16(v11, p01.v, oB, 0, 0, 0);
        }
        __builtin_amdgcn_s_setprio(0);

        // ---- SM(1)
        float cs1 = 0.f;
        union { uint32_t w[4]; short8 v; } p10, p11;
        {
            uint32_t pw[8];
            #pragma unroll
            for (int q = 0; q < 8; ++q) {
                const float pa = __builtin_amdgcn_exp2f(sx1[2 * q]);
                const float pb = __builtin_amdgcn_exp2f(sx1[2 * q + 1]);
                cs1 += pa + pb;
                pw[q] = cvtpk_bf16(pa, pb);
            }
            p10.w[0] = pw[0]; p10.w[1] = pw[1]; p10.w[2] = pw[2]; p10.w[3] = pw[3];
            p11.w[0] = pw[4]; p11.w[1] = pw[5]; p11.w[2] = pw[6]; p11.w[3] = pw[7];
        }

        // ---- PV(1)
        __builtin_amdgcn_s_setprio(1);
        {
            const short8 v00 = *(const short8*)(vb1 + 0 * 512 + lane * 8);
            oA = __builtin_amdgcn_mfma_f32_32x32x16_bf16(v00, p10.v, oA, 0, 0, 0);
            const short8 v01 = *(const short8*)(vb1 + 1 * 512 + lane * 8);
            oB = __builtin_amdgcn_mfma_f32_32x32x16_bf16(v01, p10.v, oB, 0, 0, 0);
            const short8 v10 = *(const short8*)(vb1 + 2 * 512 + lane * 8);
            oA = __builtin_amdgcn_mfma_f32_32x32x16_bf16(v10, p11.v, oA, 0, 0, 0);
            const short8 v11 = *(const short8*)(vb1 + 3 * 512 + lane * 8);
            oB = __builtin_amdgcn_mfma_f32_32x32x16_bf16(v11, p11.v, oB, 0, 0, 0);
        }
        __builtin_amdgcn_s_setprio(0);

        l_run += cs0 + cs1;
        buf ^= 1;
    }

    const float lt = l_run + __shfl_xor(l_run, 32);

    ushort_t* orow = Op + (((size_t)b * ksplit + part) * N_ + j0 + l31) * D_;
    #pragma unroll
    for (int q = 0; q < 4; ++q) {
        const int d0 = 8 * q + 4 * h2;
        uint2 ua, ub;
        ua.x = cvtpk_bf16(oA[4 * q],     oA[4 * q + 1]);
        ua.y = cvtpk_bf16(oA[4 * q + 2], oA[4 * q + 3]);
        *(uint2*)&orow[d0] = ua;
        ub.x = cvtpk_bf16(oB[4 * q],     oB[4 * q + 1]);
        ub.y = cvtpk_bf16(oB[4 * q + 2], oB[4 * q + 3]);
        *(uint2*)&orow[32 + d0] = ub;
    }
    if (h2 == 0)
        ml[((size_t)b * ksplit + part) * N_ + j0 + l31] = lt;
}

// -------------------------------------------------------------------------
// Kernel 3: fused reduce + outproj (verified R9/R10, unchanged).
// -------------------------------------------------------------------------
__global__ __launch_bounds__(512) void reduce_outproj(
    const ushort_t* __restrict__ Op, const float* __restrict__ ml,
    const float* __restrict__ wv, const float* __restrict__ bv,
    const float* __restrict__ gamma, const float* __restrict__ x,
    float* __restrict__ y, int ksplit)
{
    const int b    = blockIdx.y;
    const int n0   = blockIdx.x * 64;
    const int tid  = threadIdx.x;          // 0..511
    const int wv8  = tid >> 6;             // wave 0..7 -> co rows [wv8*64, +64)
    const int lane = tid & 63;
    const int g    = lane >> 4;
    const int r    = lane & 15;

    __shared__ ushort_t Os[64][72];        // [loc][k] normalized O tile

    {
        const int loc = tid >> 3;          // 0..63
        const int k8  = (tid & 7) * 8;     // 0..56
        float L = 0.f;
        float v[8] = {0.f, 0.f, 0.f, 0.f, 0.f, 0.f, 0.f, 0.f};
        for (int p = 0; p < ksplit; ++p) {
            const size_t base = ((size_t)b * ksplit + p) * N_ + n0 + loc;
            L += ml[base];
            uint4 u = *(const uint4*)&Op[base * D_ + k8];
            v[0] += bf2f(u.x & 0xffffu); v[1] += bf2f(u.x >> 16);
            v[2] += bf2f(u.y & 0xffffu); v[3] += bf2f(u.y >> 16);
            v[4] += bf2f(u.z & 0xffffu); v[5] += bf2f(u.z >> 16);
            v[6] += bf2f(u.w & 0xffffu); v[7] += bf2f(u.w >> 16);
        }
        const float inv = 1.0f / L;
        uint4 o;
        o.x = cvtpk_bf16(v[0] * inv, v[1] * inv);
        o.y = cvtpk_bf16(v[2] * inv, v[3] * inv);
        o.z = cvtpk_bf16(v[4] * inv, v[5] * inv);
        o.w = cvtpk_bf16(v[6] * inv, v[7] * inv);
        *(uint4*)&Os[loc][k8] = o;
    }
    __syncthreads();

    short8 a[4][2];
    #pragma unroll
    for (int cs = 0; cs < 4; ++cs) {
        const float* wrow = wv + (size_t)(wv8 * 64 + cs * 16 + r) * D_ + 8 * g;
        const float4 wa = *(const float4*)(wrow);
        const float4 wb = *(const float4*)(wrow + 4);
        const float4 wc = *(const float4*)(wrow + 32);
        const float4 wd = *(const float4*)(wrow + 36);
        uint32_t* a0 = (uint32_t*)&a[cs][0];
        uint32_t* a1 = (uint32_t*)&a[cs][1];
        a0[0] = cvtpk_bf16(wa.x, wa.y); a0[1] = cvtpk_bf16(wa.z, wa.w);
        a0[2] = cvtpk_bf16(wb.x, wb.y); a0[3] = cvtpk_bf16(wb.z, wb.w);
        a1[0] = cvtpk_bf16(wc.x, wc.y); a1[1] = cvtpk_bf16(wc.z, wc.w);
        a1[2] = cvtpk_bf16(wd.x, wd.y); a1[3] = cvtpk_bf16(wd.z, wd.w);
    }

    f32x4 acc[4][4];
    #pragma unroll
    for (int cs = 0; cs < 4; ++cs)
        #pragma unroll
        for (int t = 0; t < 4; ++t) acc[cs][t] = (f32x4){0.f, 0.f, 0.f, 0.f};

    #pragma unroll
    for (int t = 0; t < 4; ++t) {
        const short8 b0 = *(const short8*)&Os[16 * t + r][8 * g];
        const short8 b1 = *(const short8*)&Os[16 * t + r][32 + 8 * g];
        __builtin_amdgcn_s_setprio(1);
        #pragma unroll
        for (int cs = 0; cs < 4; ++cs) {
            acc[cs][t] = __builtin_amdgcn_mfma_f32_16x16x32_bf16(a[cs][0], b0, acc[cs][t], 0, 0, 0);
            acc[cs][t] = __builtin_amdgcn_mfma_f32_16x16x32_bf16(a[cs][1], b1, acc[cs][t], 0, 0, 0);
        }
        __builtin_amdgcn_s_setprio(0);
    }

    const float gm = *gamma;
    #pragma unroll
    for (int cs = 0; cs < 4; ++cs) {
        #pragma unroll
        for (int t = 0; t < 4; ++t) {
            #pragma unroll
            for (int j = 0; j < 4; ++j) {
                const int co = wv8 * 64 + cs * 16 + 4 * g + j;
                const int n  = n0 + 16 * t + r;
                const size_t idx = ((size_t)b * C_ + co) * N_ + n;
                y[idx] = gm * (acc[cs][t][j] + bv[co]) + x[idx];
            }
        }
    }
}

// -------------------------------------------------------------------------
extern "C" void kernel_launch(void* const* d_in, const int* in_sizes, int n_in,
                              void* d_out, int out_size, void* d_ws, size_t ws_size,
                              hipStream_t stream) {
    const float* x     = (const float*)d_in[0];
    const float* wf    = (const float*)d_in[1];
    const float* bf    = (const float*)d_in[2];
    const float* wg    = (const float*)d_in[3];
    const float* bg    = (const float*)d_in[4];
    const float* wh    = (const float*)d_in[5];
    const float* bh    = (const float*)d_in[6];
    const float* wv    = (const float*)d_in[7];
    const float* bv    = (const float*)d_in[8];
    const float* gamma = (const float*)d_in[9];
    float* y = (float*)d_out;

    const size_t plane = (size_t)B_ * N_ * D_;   // 1M elements
    ushort_t* Ftf = (ushort_t*)d_ws;             // pre-swizzled K fragments
    ushort_t* Gt  = Ftf + plane;                 // Q rows
    ushort_t* Vtf = Gt + plane;                  // pre-swizzled V fragments
    ushort_t* Op  = Vtf + plane;                 // split-K partials (bf16)

    int KS = 8;
    while (KS > 1) {
        const size_t need = 3 * plane * 2 + (size_t)KS * plane * 2
                          + (size_t)B_ * KS * N_ * sizeof(float);
        if (need <= ws_size) break;
        KS >>= 1;
    }
    float* ml = (float*)(Op + (size_t)KS * plane);

    proj_fgh<<<dim3(N_ / 32, B_), 512, 0, stream>>>(
        x, wf, bf, wg, bg, wh, bh, Ftf, Gt, Vtf);
    attn<<<dim3(N_ / 128, KS, B_), 256, 0, stream>>>(
        Ftf, Gt, Vtf, Op, ml, KS);
    reduce_outproj<<<dim3(N_ / 64, B_), 512, 0, stream>>>(
        Op, ml, wv, bv, gamma, x, y, KS);
}

// Round 12
// 58.309 us; speedup vs baseline: 1.1566x; 1.0079x over previous
//
#include <hip/hip_runtime.h>
#include <stdint.h>

#define B_ 4
#define C_ 512
#define N_ 4096
#define D_ 64
#define LOG2E 1.4426950408889634f

typedef __attribute__((ext_vector_type(8))) short short8;
typedef __attribute__((ext_vector_type(4))) float f32x4;
typedef __attribute__((ext_vector_type(16))) float f32x16;
typedef unsigned short ushort_t;

static __device__ __forceinline__ ushort_t f2bf(float f) {
    union { float f; uint32_t u; } v; v.f = f;
    uint32_t u = v.u;
    uint32_t r = u + 0x7FFFu + ((u >> 16) & 1u);
    return (ushort_t)(r >> 16);
}
static __device__ __forceinline__ float bf2f(uint32_t u) {
    union { uint32_t u; float f; } v; v.u = u << 16;
    return v.f;
}
static __device__ __forceinline__ uint32_t cvtpk_bf16(float lo, float hi) {
    uint32_t r;
    asm("v_cvt_pk_bf16_f32 %0, %1, %2" : "=v"(r) : "v"(lo), "v"(hi));
    return r;
}
// async global->LDS, 16B per lane. LDS dst must be wave-uniform base + lane*16.
static __device__ __forceinline__ void gl16(const ushort_t* g, ushort_t* l) {
    __builtin_amdgcn_global_load_lds(
        (const __attribute__((address_space(1))) void*)g,
        (__attribute__((address_space(3))) void*)l, 16, 0, 0);
}

// -------------------------------------------------------------------------
// Kernel 1: merged F/G/H projections, 32-loc tiles (R10 config, verified).
// -------------------------------------------------------------------------
__global__ __launch_bounds__(512) void proj_fgh(
    const float* __restrict__ x,
    const float* __restrict__ wf, const float* __restrict__ bf,
    const float* __restrict__ wg, const float* __restrict__ bg,
    const float* __restrict__ wh, const float* __restrict__ bh,
    ushort_t* __restrict__ Ftf, ushort_t* __restrict__ Gt,
    ushort_t* __restrict__ Vtf)
{
    const int b    = blockIdx.y;
    const int nb   = blockIdx.x;           // 0..127
    const int tile = nb >> 1;              // 64-key tile index
    const int cc   = nb & 1;               // which 32-half of the tile
    const int n0   = nb * 32;
    const int tid  = threadIdx.x;          // 0..511
    const int wv   = tid >> 6;             // 0..7
    const int mw   = wv & 1;               // m-tile (16 locs)
    const int hi   = wv >> 1;              // o-group 0..3
    const int lane = tid & 63;
    const int g    = lane >> 4;
    const int r    = lane & 15;

    __shared__ ushort_t As[32][40];        // [loc][k]
    __shared__ ushort_t Bs[192][40];       // [o][k]

    f32x4 acc[3];
    #pragma unroll
    for (int t = 0; t < 3; ++t) acc[t] = (f32x4){0.f, 0.f, 0.f, 0.f};

    const int ka = tid >> 4;               // 0..31 (k row)
    const int mb = (tid & 15) * 2;         // 0..30 (2 locs)
    const int ow = tid >> 3;               // 0..63 (o row within group)
    const int kb = (tid & 7) * 4;          // 0..28

    const float* xp  = x  + ((size_t)b * C_ + ka) * N_ + n0 + mb;
    const float* wp0 = wf + (size_t)ow * C_ + kb;
    const float* wp1 = wg + (size_t)ow * C_ + kb;
    const float* wp2 = wh + (size_t)ow * C_ + kb;

    float2 xa = *(const float2*)xp;
    float4 w0 = *(const float4*)wp0;
    float4 w1 = *(const float4*)wp1;
    float4 w2 = *(const float4*)wp2;

    for (int k0 = 0; k0 < C_; k0 += 32) {
        As[mb + 0][ka] = f2bf(xa.x);
        As[mb + 1][ka] = f2bf(xa.y);
        {
            uint2 p0, p1, p2;
            p0.x = cvtpk_bf16(w0.x, w0.y); p0.y = cvtpk_bf16(w0.z, w0.w);
            p1.x = cvtpk_bf16(w1.x, w1.y); p1.y = cvtpk_bf16(w1.z, w1.w);
            p2.x = cvtpk_bf16(w2.x, w2.y); p2.y = cvtpk_bf16(w2.z, w2.w);
            *(uint2*)&Bs[ow][kb]       = p0;
            *(uint2*)&Bs[64 + ow][kb]  = p1;
            *(uint2*)&Bs[128 + ow][kb] = p2;
        }
        if (k0 + 32 < C_) {
            xa = *(const float2*)(xp + (size_t)(k0 + 32) * N_);
            w0 = *(const float4*)(wp0 + k0 + 32);
            w1 = *(const float4*)(wp1 + k0 + 32);
            w2 = *(const float4*)(wp2 + k0 + 32);
        }
        __syncthreads();
        short8 a = *(const short8*)&As[16 * mw + r][8 * g];
        __builtin_amdgcn_s_setprio(1);
        #pragma unroll
        for (int tt = 0; tt < 3; ++tt) {
            const int T = tt * 4 + hi;
            short8 bbv = *(const short8*)&Bs[T * 16 + r][8 * g];
            acc[tt] = __builtin_amdgcn_mfma_f32_16x16x32_bf16(a, bbv, acc[tt], 0, 0, 0);
        }
        __builtin_amdgcn_s_setprio(0);
        __syncthreads();
    }

    // ---- G (tt=1): direct store, o = hi*16 + r
    {
        const int og = hi * 16 + r;
        const float bvv = bg[og];
        #pragma unroll
        for (int j = 0; j < 4; ++j) {
            const int loc = n0 + 16 * mw + 4 * g + j;
            Gt[((size_t)b * N_ + loc) * D_ + og] = f2bf(acc[1][j] + bvv);
        }
    }

    ushort_t (*bbF)[72] = (ushort_t(*)[72])&Bs[0][0];
    ushort_t (*bbH)[72] = (ushort_t(*)[72])(&Bs[0][0] + 32 * 72);

    {
        const int o = hi * 16 + r;
        const float bvv = bf[o];
        #pragma unroll
        for (int j = 0; j < 4; ++j)
            bbF[16 * mw + 4 * g + j][o] = f2bf((acc[0][j] + bvv) * LOG2E);
    }
    {
        const int o = hi * 16 + r;
        const float bvv = bh[o];
        #pragma unroll
        for (int j = 0; j < 4; ++j)
            bbH[16 * mw + 4 * g + j][o] = f2bf(acc[2][j] + bvv);
    }
    __syncthreads();

    if (tid < 256) {
        const int s = (tid >> 6) & 3;          // d-slab
        const int l = tid & 63;
        short8 v = *(const short8*)&bbF[l & 31][16 * s + 8 * (l >> 5)];
        const int f = cc * 4 + s;
        *(short8*)&Ftf[(((size_t)b * 64 + tile) * 8 + f) * 512 + l * 8] = v;
    } else {
        const int u   = tid & 255;
        const int fi  = u >> 6;                // sub*2 + dt
        const int sub = fi >> 1, dt = fi & 1;
        const int l   = u & 63;
        const int h2l = l >> 5;
        short8 v;
        #pragma unroll
        for (int e = 0; e < 8; ++e) {
            const int i = 16 * sub + (e & 3) + 8 * (e >> 2) + 4 * h2l;
            v[e] = (short)bbH[i][32 * dt + (l & 31)];
        }
        const int f = cc * 4 + sub * 2 + dt;
        *(short8*)&Vtf[(((size_t)b * 64 + tile) * 8 + f) * 512 + l * 8] = v;
    }
}

// -------------------------------------------------------------------------
// Kernel 2: flash attention — R11 structure + PHASE-STAGGERED tile order.
// Each block starts its key-tile walk at t0 = hash(block) & (NT-1) and wraps.
// Legal: max-free softmax and PV accumulation are commutative over keys.
// Purpose: de-phase co-resident blocks (break lockstep exp/MFMA bursts on
// shared SIMD pipes) and spread L2 reads across the K/V slab.
// -------------------------------------------------------------------------
__global__ __launch_bounds__(256, 4) void attn(
    const ushort_t* __restrict__ Ftf, const ushort_t* __restrict__ Gt,
    const ushort_t* __restrict__ Vtf,
    ushort_t* __restrict__ Op, float* __restrict__ ml, int ksplit)
{
    const int b    = blockIdx.z;
    const int part = blockIdx.y;
    const int tid  = threadIdx.x;
    const int lane = tid & 63;
    const int wave = tid >> 6;
    const int l31  = lane & 31;
    const int h2   = lane >> 5;
    const int j0   = blockIdx.x * 128 + wave * 32;
    const int NT   = (N_ / ksplit) / 64;
    const int kt0  = part * NT;
    // per-block phase stagger (NT is a power of two)
    const int t0   = (blockIdx.x * 5 + part * 3 + b) & (NT - 1);

    __shared__ __align__(16) ushort_t Ks[2][4096];
    __shared__ __align__(16) ushort_t Vs[2][4096];

    const ushort_t* qrow = Gt + ((size_t)b * N_ + j0 + l31) * D_ + 8 * h2;
    const short8 qf0 = *(const short8*)(qrow);
    const short8 qf1 = *(const short8*)(qrow + 16);
    const short8 qf2 = *(const short8*)(qrow + 32);
    const short8 qf3 = *(const short8*)(qrow + 48);

    const ushort_t* Kt = Ftf + ((size_t)b * 64 + kt0) * 4096;
    const ushort_t* Vt = Vtf + ((size_t)b * 64 + kt0) * 4096;

    f32x16 oA, oB;
    #pragma unroll
    for (int q = 0; q < 16; ++q) { oA[q] = 0.f; oB[q] = 0.f; }
    float l_run = 0.f;

    // prologue: stage tile t0 -> buf 0
    {
        const size_t off = (size_t)t0 * 4096;
        gl16(Kt + off + tid * 8,         &Ks[0][tid * 8]);
        gl16(Kt + off + (tid + 256) * 8, &Ks[0][(tid + 256) * 8]);
        gl16(Vt + off + tid * 8,         &Vs[0][tid * 8]);
        gl16(Vt + off + (tid + 256) * 8, &Vs[0][(tid + 256) * 8]);
    }

    int buf = 0;
    for (int t = 0; t < NT; ++t) {
        __syncthreads();   // drains current tile's DMA (issued a full iter ago)
        if (t + 1 < NT) {
            int nt = t + 1 + t0; if (nt >= NT) nt -= NT;
            const ushort_t* kg = Kt + (size_t)nt * 4096;
            const ushort_t* vg = Vt + (size_t)nt * 4096;
            const int nb = buf ^ 1;
            gl16(kg + tid * 8,         &Ks[nb][tid * 8]);
            gl16(kg + (tid + 256) * 8, &Ks[nb][(tid + 256) * 8]);
            gl16(vg + tid * 8,         &Vs[nb][tid * 8]);
            gl16(vg + (tid + 256) * 8, &Vs[nb][(tid + 256) * 8]);
        }

        const ushort_t* kb0 = &Ks[buf][0];
        const ushort_t* kb1 = &Ks[buf][2048];
        const ushort_t* vb0 = &Vs[buf][0];
        const ushort_t* vb1 = &Vs[buf][2048];

        // ---- S(0) then S(1): both score MFMAs issued before any softmax
        f32x16 sx0, sx1;
        #pragma unroll
        for (int q = 0; q < 16; ++q) { sx0[q] = 0.f; sx1[q] = 0.f; }
        __builtin_amdgcn_s_setprio(1);
        {
            const short8 ka0 = *(const short8*)(kb0 + 0 * 512 + lane * 8);
            sx0 = __builtin_amdgcn_mfma_f32_32x32x16_bf16(ka0, qf0, sx0, 0, 0, 0);
            const short8 ka1 = *(const short8*)(kb0 + 1 * 512 + lane * 8);
            sx0 = __builtin_amdgcn_mfma_f32_32x32x16_bf16(ka1, qf1, sx0, 0, 0, 0);
            const short8 ka2 = *(const short8*)(kb0 + 2 * 512 + lane * 8);
            sx0 = __builtin_amdgcn_mfma_f32_32x32x16_bf16(ka2, qf2, sx0, 0, 0, 0);
            const short8 ka3 = *(const short8*)(kb0 + 3 * 512 + lane * 8);
            sx0 = __builtin_amdgcn_mfma_f32_32x32x16_bf16(ka3, qf3, sx0, 0, 0, 0);
            const short8 kb0f = *(const short8*)(kb1 + 0 * 512 + lane * 8);
            sx1 = __builtin_amdgcn_mfma_f32_32x32x16_bf16(kb0f, qf0, sx1, 0, 0, 0);
            const short8 kb1f = *(const short8*)(kb1 + 1 * 512 + lane * 8);
            sx1 = __builtin_amdgcn_mfma_f32_32x32x16_bf16(kb1f, qf1, sx1, 0, 0, 0);
            const short8 kb2f = *(const short8*)(kb1 + 2 * 512 + lane * 8);
            sx1 = __builtin_amdgcn_mfma_f32_32x32x16_bf16(kb2f, qf2, sx1, 0, 0, 0);
            const short8 kb3f = *(const short8*)(kb1 + 3 * 512 + lane * 8);
            sx1 = __builtin_amdgcn_mfma_f32_32x32x16_bf16(kb3f, qf3, sx1, 0, 0, 0);
        }
        __builtin_amdgcn_s_setprio(0);

        // ---- SM(0): overlaps S(1) MFMAs still in the matrix pipe
        float cs0 = 0.f;
        union { uint32_t w[4]; short8 v; } p00, p01;
        {
            uint32_t pw[8];
            #pragma unroll
            for (int q = 0; q < 8; ++q) {
                const float pa = __builtin_amdgcn_exp2f(sx0[2 * q]);
                const float pb = __builtin_amdgcn_exp2f(sx0[2 * q + 1]);
                cs0 += pa + pb;
                pw[q] = cvtpk_bf16(pa, pb);
            }
            p00.w[0] = pw[0]; p00.w[1] = pw[1]; p00.w[2] = pw[2]; p00.w[3] = pw[3];
            p01.w[0] = pw[4]; p01.w[1] = pw[5]; p01.w[2] = pw[6]; p01.w[3] = pw[7];
        }

        // ---- PV(0): matrix pipe; SM(1) below overlaps these MFMAs
        __builtin_amdgcn_s_setprio(1);
        {
            const short8 v00 = *(const short8*)(vb0 + 0 * 512 + lane * 8);
            oA = __builtin_amdgcn_mfma_f32_32x32x16_bf16(v00, p00.v, oA, 0, 0, 0);
            const short8 v01 = *(const short8*)(vb0 + 1 * 512 + lane * 8);
            oB = __builtin_amdgcn_mfma_f32_32x32x16_bf16(v01, p00.v, oB, 0, 0, 0);
            const short8 v10 = *(const short8*)(vb0 + 2 * 512 + lane * 8);
            oA = __builtin_amdgcn_mfma_f32_32x32x16_bf16(v10, p01.v, oA, 0, 0, 0);
            const short8 v11 = *(const short8*)(vb0 + 3 * 512 + lane * 8);
            oB = __builtin_amdgcn_mfma_f32_32x32x16_bf16(v11, p01.v, oB, 0, 0, 0);
        }
        __builtin_amdgcn_s_setprio(0);

        // ---- SM(1)
        float cs1 = 0.f;
        union { uint32_t w[4]; short8 v; } p10, p11;
        {
            uint32_t pw[8];
            #pragma unroll
            for (int q = 0; q < 8; ++q) {
                const float pa = __builtin_amdgcn_exp2f(sx1[2 * q]);
                const float pb = __builtin_amdgcn_exp2f(sx1[2 * q + 1]);
                cs1 += pa + pb;
                pw[q] = cvtpk_bf16(pa, pb);
            }
            p10.w[0] = pw[0]; p10.w[1] = pw[1]; p10.w[2] = pw[2]; p10.w[3] = pw[3];
            p11.w[0] = pw[4]; p11.w[1] = pw[5]; p11.w[2] = pw[6]; p11.w[3] = pw[7];
        }

        // ---- PV(1)
        __builtin_amdgcn_s_setprio(1);
        {
            const short8 v00 = *(const short8*)(vb1 + 0 * 512 + lane * 8);
            oA = __builtin_amdgcn_mfma_f32_32x32x16_bf16(v00, p10.v, oA, 0, 0, 0);
            const short8 v01 = *(const short8*)(vb1 + 1 * 512 + lane * 8);
            oB = __builtin_amdgcn_mfma_f32_32x32x16_bf16(v01, p10.v, oB, 0, 0, 0);
            const short8 v10 = *(const short8*)(vb1 + 2 * 512 + lane * 8);
            oA = __builtin_amdgcn_mfma_f32_32x32x16_bf16(v10, p11.v, oA, 0, 0, 0);
            const short8 v11 = *(const short8*)(vb1 + 3 * 512 + lane * 8);
            oB = __builtin_amdgcn_mfma_f32_32x32x16_bf16(v11, p11.v, oB, 0, 0, 0);
        }
        __builtin_amdgcn_s_setprio(0);

        l_run += cs0 + cs1;
        buf ^= 1;
    }

    const float lt = l_run + __shfl_xor(l_run, 32);

    ushort_t* orow = Op + (((size_t)b * ksplit + part) * N_ + j0 + l31) * D_;
    #pragma unroll
    for (int q = 0; q < 4; ++q) {
        const int d0 = 8 * q + 4 * h2;
        uint2 ua, ub;
        ua.x = cvtpk_bf16(oA[4 * q],     oA[4 * q + 1]);
        ua.y = cvtpk_bf16(oA[4 * q + 2], oA[4 * q + 3]);
        *(uint2*)&orow[d0] = ua;
        ub.x = cvtpk_bf16(oB[4 * q],     oB[4 * q + 1]);
        ub.y = cvtpk_bf16(oB[4 * q + 2], oB[4 * q + 3]);
        *(uint2*)&orow[32 + d0] = ub;
    }
    if (h2 == 0)
        ml[((size_t)b * ksplit + part) * N_ + j0 + l31] = lt;
}

// -------------------------------------------------------------------------
// Kernel 3: fused reduce + outproj (verified R9-R11, unchanged).
// -------------------------------------------------------------------------
__global__ __launch_bounds__(512) void reduce_outproj(
    const ushort_t* __restrict__ Op, const float* __restrict__ ml,
    const float* __restrict__ wv, const float* __restrict__ bv,
    const float* __restrict__ gamma, const float* __restrict__ x,
    float* __restrict__ y, int ksplit)
{
    const int b    = blockIdx.y;
    const int n0   = blockIdx.x * 64;
    const int tid  = threadIdx.x;          // 0..511
    const int wv8  = tid >> 6;             // wave 0..7 -> co rows [wv8*64, +64)
    const int lane = tid & 63;
    const int g    = lane >> 4;
    const int r    = lane & 15;

    __shared__ ushort_t Os[64][72];        // [loc][k] normalized O tile

    {
        const int loc = tid >> 3;          // 0..63
        const int k8  = (tid & 7) * 8;     // 0..56
        float L = 0.f;
        float v[8] = {0.f, 0.f, 0.f, 0.f, 0.f, 0.f, 0.f, 0.f};
        for (int p = 0; p < ksplit; ++p) {
            const size_t base = ((size_t)b * ksplit + p) * N_ + n0 + loc;
            L += ml[base];
            uint4 u = *(const uint4*)&Op[base * D_ + k8];
            v[0] += bf2f(u.x & 0xffffu); v[1] += bf2f(u.x >> 16);
            v[2] += bf2f(u.y & 0xffffu); v[3] += bf2f(u.y >> 16);
            v[4] += bf2f(u.z & 0xffffu); v[5] += bf2f(u.z >> 16);
            v[6] += bf2f(u.w & 0xffffu); v[7] += bf2f(u.w >> 16);
        }
        const float inv = 1.0f / L;
        uint4 o;
        o.x = cvtpk_bf16(v[0] * inv, v[1] * inv);
        o.y = cvtpk_bf16(v[2] * inv, v[3] * inv);
        o.z = cvtpk_bf16(v[4] * inv, v[5] * inv);
        o.w = cvtpk_bf16(v[6] * inv, v[7] * inv);
        *(uint4*)&Os[loc][k8] = o;
    }
    __syncthreads();

    short8 a[4][2];
    #pragma unroll
    for (int cs = 0; cs < 4; ++cs) {
        const float* wrow = wv + (size_t)(wv8 * 64 + cs * 16 + r) * D_ + 8 * g;
        const float4 wa = *(const float4*)(wrow);
        const float4 wb = *(const float4*)(wrow + 4);
        const float4 wc = *(const float4*)(wrow + 32);
        const float4 wd = *(const float4*)(wrow + 36);
        uint32_t* a0 = (uint32_t*)&a[cs][0];
        uint32_t* a1 = (uint32_t*)&a[cs][1];
        a0[0] = cvtpk_bf16(wa.x, wa.y); a0[1] = cvtpk_bf16(wa.z, wa.w);
        a0[2] = cvtpk_bf16(wb.x, wb.y); a0[3] = cvtpk_bf16(wb.z, wb.w);
        a1[0] = cvtpk_bf16(wc.x, wc.y); a1[1] = cvtpk_bf16(wc.z, wc.w);
        a1[2] = cvtpk_bf16(wd.x, wd.y); a1[3] = cvtpk_bf16(wd.z, wd.w);
    }

    f32x4 acc[4][4];
    #pragma unroll
    for (int cs = 0; cs < 4; ++cs)
        #pragma unroll
        for (int t = 0; t < 4; ++t) acc[cs][t] = (f32x4){0.f, 0.f, 0.f, 0.f};

    #pragma unroll
    for (int t = 0; t < 4; ++t) {
        const short8 b0 = *(const short8*)&Os[16 * t + r][8 * g];
        const short8 b1 = *(const short8*)&Os[16 * t + r][32 + 8 * g];
        __builtin_amdgcn_s_setprio(1);
        #pragma unroll
        for (int cs = 0; cs < 4; ++cs) {
            acc[cs][t] = __builtin_amdgcn_mfma_f32_16x16x32_bf16(a[cs][0], b0, acc[cs][t], 0, 0, 0);
            acc[cs][t] = __builtin_amdgcn_mfma_f32_16x16x32_bf16(a[cs][1], b1, acc[cs][t], 0, 0, 0);
        }
        __builtin_amdgcn_s_setprio(0);
    }

    const float gm = *gamma;
    #pragma unroll
    for (int cs = 0; cs < 4; ++cs) {
        #pragma unroll
        for (int t = 0; t < 4; ++t) {
            #pragma unroll
            for (int j = 0; j < 4; ++j) {
                const int co = wv8 * 64 + cs * 16 + 4 * g + j;
                const int n  = n0 + 16 * t + r;
                const size_t idx = ((size_t)b * C_ + co) * N_ + n;
                y[idx] = gm * (acc[cs][t][j] + bv[co]) + x[idx];
            }
        }
    }
}

// -------------------------------------------------------------------------
extern "C" void kernel_launch(void* const* d_in, const int* in_sizes, int n_in,
                              void* d_out, int out_size, void* d_ws, size_t ws_size,
                              hipStream_t stream) {
    const float* x     = (const float*)d_in[0];
    const float* wf    = (const float*)d_in[1];
    const float* bf    = (const float*)d_in[2];
    const float* wg    = (const float*)d_in[3];
    const float* bg    = (const float*)d_in[4];
    const float* wh    = (const float*)d_in[5];
    const float* bh    = (const float*)d_in[6];
    const float* wv    = (const float*)d_in[7];
    const float* bv    = (const float*)d_in[8];
    const float* gamma = (const float*)d_in[9];
    float* y = (float*)d_out;

    const size_t plane = (size_t)B_ * N_ * D_;   // 1M elements
    ushort_t* Ftf = (ushort_t*)d_ws;             // pre-swizzled K fragments
    ushort_t* Gt  = Ftf + plane;                 // Q rows
    ushort_t* Vtf = Gt + plane;                  // pre-swizzled V fragments
    ushort_t* Op  = Vtf + plane;                 // split-K partials (bf16)

    int KS = 8;
    while (KS > 1) {
        const size_t need = 3 * plane * 2 + (size_t)KS * plane * 2
                          + (size_t)B_ * KS * N_ * sizeof(float);
        if (need <= ws_size) break;
        KS >>= 1;
    }
    float* ml = (float*)(Op + (size_t)KS * plane);

    proj_fgh<<<dim3(N_ / 32, B_), 512, 0, stream>>>(
        x, wf, bf, wg, bg, wh, bh, Ftf, Gt, Vtf);
    attn<<<dim3(N_ / 128, KS, B_), 256, 0, stream>>>(
        Ftf, Gt, Vtf, Op, ml, KS);
    reduce_outproj<<<dim3(N_ / 64, B_), 512, 0, stream>>>(
        Op, ml, wv, bv, gamma, x, y, KS);
}